// Round 16
// baseline (754.947 us; speedup 1.0000x reference)
//
#include <hip/hip_runtime.h>
#include <stdint.h>

typedef unsigned short u16;
typedef unsigned int   u32;
typedef __attribute__((ext_vector_type(8))) short bf16x8;
typedef __attribute__((ext_vector_type(4))) float f32x4;

#define NS      63
#define NSEQ    1024
#define DDIM    256
#define NHEAD   4
#define DHEAD   64
#define UPDIM   384
#define PREDN   96
#define LLEN    512
#define CCH     32
#define PSIZE   16
#define PSTRIDE 8
#define KC_PROJ 8
#define KCHUNK_PROJ 2016

__device__ __forceinline__ float bf2f(u32 lo16){
  union { u32 i; float f; } v; v.i = lo16 << 16; return v.f;
}
__device__ __forceinline__ float bf2f_hi(u32 u){
  union { u32 i; float f; } v; v.i = u & 0xffff0000u; return v.f;
}
__device__ __forceinline__ u16 f2bf(float f){
  union { u32 i; float f; } v; v.f = f;
  u32 u = v.i; u += 0x7fffu + ((u >> 16) & 1u);
  return (u16)(u >> 16);
}

__device__ __forceinline__ void gload16(const u16* g, u16* lds){
  __builtin_amdgcn_global_load_lds(
      (const __attribute__((address_space(1))) u32*)g,
      (__attribute__((address_space(3))) u32*)lds, 16, 0, 0);
}

template<int N> __device__ __forceinline__ void waitcnt_vm(){
  if constexpr (N == 0) asm volatile("s_waitcnt vmcnt(0)" ::: "memory");
  else if constexpr (N == 4) asm volatile("s_waitcnt vmcnt(4)" ::: "memory");
  else if constexpr (N == 6) asm volatile("s_waitcnt vmcnt(6)" ::: "memory");
}

// bijective XCD swizzle (m204)
__device__ __forceinline__ void swz_tile(int &nt, int &mt){
  int gx = gridDim.x, gy = gridDim.y;
  int nwg = gx*gy;
  int flat = blockIdx.y*gx + blockIdx.x;
  int c = flat & 7, s = flat >> 3;
  int q = nwg >> 3, r = nwg & 7;
  int base = c*q + (c < r ? c : r);
  int t = base + s;
  nt = t % gx; mt = t / gx;
}

// ---------------- LDS-tiled transpose: dst[c][r] = bf16(src[r][c]) -----------------
__global__ __launch_bounds__(256) void cvt_transpose_t(
    const float* __restrict__ src, u16* __restrict__ dst, int R, int C){
  __shared__ u16 tile[32][33];
  int rb = blockIdx.x*32, cb = blockIdx.y*32;
  int tx = threadIdx.x & 31, ty = threadIdx.x >> 5;
  #pragma unroll
  for (int i = ty; i < 32; i += 8){
    int r = rb + i, c = cb + tx;
    tile[i][tx] = (r < R && c < C) ? f2bf(src[(size_t)r*C + c]) : (u16)0;
  }
  __syncthreads();
  #pragma unroll
  for (int i = ty; i < 32; i += 8){
    int c = cb + i, r = rb + tx;
    if (c < C && r < R) dst[(size_t)c*R + r] = tile[tx][i];
  }
}

__global__ __launch_bounds__(256) void cvt_gate(
    const float* __restrict__ src, u16* __restrict__ dst){
  int mat = blockIdx.x, t = threadIdx.x;
  const float* s = src + (size_t)mat*4096;
  u16* d = dst + (size_t)mat*4096;
  for (int i = t; i < 4096; i += 256){
    int r = i >> 6, c = i & 63;
    d[c*64 + r] = f2bf(s[i]);
  }
}

// gate weight true-K layout, col order n = e*2+gl: dst[(blk*2+p)*4+hd][n][k]
__global__ __launch_bounds__(256) void cvt_gateW2(
    const float* __restrict__ Wg, u16* __restrict__ dst){
  int mi = blockIdx.x;
  int blk = mi >> 3, p = (mi >> 2) & 1, hd = mi & 3;
  u16* d = dst + (size_t)mi*8192;
  for (int i = threadIdx.x; i < 8192; i += 256){
    int n = i >> 6, k = i & 63;
    int e = n >> 1, gl = n & 1;
    int g = 2*p + gl;
    d[i] = f2bf(Wg[((((size_t)blk*4 + g)*4 + hd)*64 + k)*64 + e]);
  }
}

// ---------------- patch embedding + ln1(blk0), wave = token, vectorized ------------
__global__ __launch_bounds__(256) void patch_embed_ln_v(
    const float* __restrict__ x, const float* __restrict__ Wemb,
    const float* __restrict__ bemb, const float* __restrict__ w1,
    const float* __restrict__ b1, u16* __restrict__ h,
    u16* __restrict__ outA, int t_base){
  int wv = blockIdx.x*4 + (threadIdx.x >> 6);
  int lane = threadIdx.x & 63;
  int tg = t_base + wv;
  int n = tg / NS, s = tg - n*NS;
  int b = n >> 5, c = n & 31;
  int l0 = s * PSTRIDE;
  float4 acc = *(const float4*)(bemb + lane*4);
  #pragma unroll
  for (int p = 0; p < PSIZE; ++p){
    float xv = x[((size_t)b*LLEN + l0 + p)*CCH + c];
    float4 we = *(const float4*)(Wemb + p*DDIM + lane*4);
    acc.x += xv*we.x; acc.y += xv*we.y; acc.z += xv*we.z; acc.w += xv*we.w;
  }
  ushort4 hu; hu.x=f2bf(acc.x); hu.y=f2bf(acc.y); hu.z=f2bf(acc.z); hu.w=f2bf(acc.w);
  *(ushort4*)(h + (size_t)wv*DDIM + lane*4) = hu;
  float s1 = acc.x+acc.y+acc.z+acc.w;
  float s2 = acc.x*acc.x+acc.y*acc.y+acc.z*acc.z+acc.w*acc.w;
  #pragma unroll
  for (int o = 1; o < 64; o <<= 1){ s1 += __shfl_xor(s1,o,64); s2 += __shfl_xor(s2,o,64); }
  float mu = s1*(1.f/DDIM);
  float var = s2*(1.f/DDIM) - mu*mu;
  float rstd = rsqrtf(var + 1e-5f);
  float4 wf = *(const float4*)(w1 + lane*4);
  float4 bf = *(const float4*)(b1 + lane*4);
  ushort4 o4;
  o4.x = f2bf((acc.x-mu)*rstd*wf.x + bf.x);
  o4.y = f2bf((acc.y-mu)*rstd*wf.y + bf.y);
  o4.z = f2bf((acc.z-mu)*rstd*wf.z + bf.z);
  o4.w = f2bf((acc.w-mu)*rstd*wf.w + bf.w);
  *(ushort4*)(outA + (size_t)wv*DDIM + lane*4) = o4;
}

// ---------------- layernorm, wave = token, vectorized ------------------------------
__global__ __launch_bounds__(256) void layernorm_v(
    const u16* __restrict__ in, const float* __restrict__ w,
    const float* __restrict__ b, u16* __restrict__ out){
  int wv = blockIdx.x*4 + (threadIdx.x >> 6);
  int lane = threadIdx.x & 63;
  ushort4 u = *(const ushort4*)(in + (size_t)wv*DDIM + lane*4);
  float v0=bf2f(u.x), v1=bf2f(u.y), v2=bf2f(u.z), v3=bf2f(u.w);
  float s1 = v0+v1+v2+v3, s2 = v0*v0+v1*v1+v2*v2+v3*v3;
  #pragma unroll
  for (int o = 1; o < 64; o <<= 1){ s1 += __shfl_xor(s1,o,64); s2 += __shfl_xor(s2,o,64); }
  float mu = s1*(1.f/DDIM);
  float var = s2*(1.f/DDIM) - mu*mu;
  float rstd = rsqrtf(var + 1e-5f);
  float4 wf = *(const float4*)(w + lane*4);
  float4 bf = *(const float4*)(b + lane*4);
  ushort4 o4;
  o4.x = f2bf((v0-mu)*rstd*wf.x + bf.x);
  o4.y = f2bf((v1-mu)*rstd*wf.y + bf.y);
  o4.z = f2bf((v2-mu)*rstd*wf.z + bf.z);
  o4.w = f2bf((v3-mu)*rstd*wf.w + bf.w);
  *(ushort4*)(out + (size_t)wv*DDIM + lane*4) = o4;
}

// ---------------- fused groupnorm + residual + layernorm, vectorized ---------------
__global__ __launch_bounds__(256) void gn_res_ln_v(
    const u16* __restrict__ y, const float* __restrict__ gnw,
    const float* __restrict__ w2, const float* __restrict__ b2,
    u16* __restrict__ h, u16* __restrict__ outA){
  int wv = blockIdx.x*4 + (threadIdx.x >> 6);
  int lane = threadIdx.x & 63;
  ushort4 u = *(const ushort4*)(y + (size_t)wv*DDIM + lane*4);
  float v0=bf2f(u.x), v1=bf2f(u.y), v2=bf2f(u.z), v3=bf2f(u.w);
  float s1 = v0+v1+v2+v3, s2 = v0*v0+v1*v1+v2*v2+v3*v3;
  #pragma unroll
  for (int o = 1; o < 16; o <<= 1){ s1 += __shfl_xor(s1,o,64); s2 += __shfl_xor(s2,o,64); }
  float mu64 = s1*(1.f/64.f);
  float var64 = s2*(1.f/64.f) - mu64*mu64;
  float rstd64 = rsqrtf(var64 + 1e-5f);
  float4 gw = *(const float4*)(gnw + lane*4);
  ushort4 hu = *(const ushort4*)(h + (size_t)wv*DDIM + lane*4);
  float h0 = bf2f(hu.x) + (v0-mu64)*rstd64*gw.x;
  float h1 = bf2f(hu.y) + (v1-mu64)*rstd64*gw.y;
  float h2 = bf2f(hu.z) + (v2-mu64)*rstd64*gw.z;
  float h3 = bf2f(hu.w) + (v3-mu64)*rstd64*gw.w;
  ushort4 hn; hn.x=f2bf(h0); hn.y=f2bf(h1); hn.z=f2bf(h2); hn.w=f2bf(h3);
  *(ushort4*)(h + (size_t)wv*DDIM + lane*4) = hn;
  float t1 = h0+h1+h2+h3, t2 = h0*h0+h1*h1+h2*h2+h3*h3;
  #pragma unroll
  for (int o = 1; o < 64; o <<= 1){ t1 += __shfl_xor(t1,o,64); t2 += __shfl_xor(t2,o,64); }
  float mu = t1*(1.f/DDIM);
  float var = t2*(1.f/DDIM) - mu*mu;
  float rstd = rsqrtf(var + 1e-5f);
  float4 wf = *(const float4*)(w2 + lane*4);
  float4 bf = *(const float4*)(b2 + lane*4);
  ushort4 o4;
  o4.x = f2bf((h0-mu)*rstd*wf.x + bf.x);
  o4.y = f2bf((h1-mu)*rstd*wf.y + bf.y);
  o4.z = f2bf((h2-mu)*rstd*wf.z + bf.z);
  o4.w = f2bf((h3-mu)*rstd*wf.w + bf.w);
  *(ushort4*)(outA + (size_t)wv*DDIM + lane*4) = o4;
}

// ---------------- generic MFMA GEMM (XCD-swizzled) ---------------------------------
template<int BM,int BN,int WR,int WC,int MR,int NR,int MODE,int VM>
__global__ __launch_bounds__(256) void mfma_gemm2(
    const u16* __restrict__ A, int lda,
    const u16* __restrict__ Wt, int ldwt,
    const float* __restrict__ bias, void* __restrict__ outp, int ldo,
    int ksteps, int kchunk, int Mtot)
{
  constexpr int nA = BM/16, nW = BN/16;
  __shared__ u16 As[2][BM*32];
  __shared__ u16 Ws[2][BN*32];
  const int tid = threadIdx.x;
  const int lane = tid & 63, wid = tid >> 6;
  const int wr = wid / WC, wc = wid % WC;
  const int fr = lane & 15, kb = lane >> 4;
  int nt, mt; swz_tile(nt, mt);
  const int m0 = mt*BM, n0 = nt*BN;
  const int kc = blockIdx.z;
  const int kbeg = kc*kchunk;
  const u16* Ab = A + (size_t)m0*lda + kbeg;
  const u16* Wb = Wt + (size_t)n0*ldwt + kbeg;
  const int lrow = lane >> 2, lcol = (lane & 3)*8;

  auto stage = [&](int buf, int ks){
    int k0 = ks*32;
    for (int c = wid; c < nA; c += 4)
      gload16(Ab + (size_t)(c*16 + lrow)*lda + k0 + lcol, &As[buf][c*512]);
    for (int c = wid; c < nW; c += 4)
      gload16(Wb + (size_t)(c*16 + lrow)*ldwt + k0 + lcol, &Ws[buf][c*512]);
  };

  f32x4 acc[MR][NR];
  #pragma unroll
  for (int m=0;m<MR;++m)
    #pragma unroll
    for (int n=0;n<NR;++n) acc[m][n] = (f32x4){0.f,0.f,0.f,0.f};

  stage(0, 0);
  if (VM == 0) __syncthreads();
  int cur = 0;
  for (int ks = 0; ks < ksteps; ++ks){
    if (VM == 0){
      if (ks + 1 < ksteps) stage(cur^1, ks+1);
    } else {
      if (ks + 1 < ksteps){ stage(cur^1, ks+1); waitcnt_vm<VM>(); }
      else waitcnt_vm<0>();
      __builtin_amdgcn_s_barrier();
      asm volatile("" ::: "memory");
    }
    bf16x8 af[MR], wf[NR];
    #pragma unroll
    for (int m=0;m<MR;++m)
      af[m] = *(const bf16x8*)&As[cur][(wr*MR*16 + m*16 + fr)*32 + kb*8];
    #pragma unroll
    for (int n=0;n<NR;++n)
      wf[n] = *(const bf16x8*)&Ws[cur][(wc*NR*16 + n*16 + fr)*32 + kb*8];
    #pragma unroll
    for (int m=0;m<MR;++m)
      #pragma unroll
      for (int n=0;n<NR;++n)
        acc[m][n] = __builtin_amdgcn_mfma_f32_16x16x32_bf16(af[m], wf[n], acc[m][n], 0,0,0);
    if (VM == 0){
      __syncthreads();
    } else {
      asm volatile("" ::: "memory");
      __builtin_amdgcn_s_barrier();
    }
    cur ^= 1;
  }
  #pragma unroll
  for (int m=0;m<MR;++m){
    int rowb = m0 + wr*MR*16 + m*16 + kb*4;
    #pragma unroll
    for (int n=0;n<NR;++n){
      int col = n0 + wc*NR*16 + n*16 + fr;
      #pragma unroll
      for (int r=0;r<4;++r){
        int row = rowb + r;
        float v = acc[m][n][r];
        if (MODE == 1){
          u16* dst = (u16*)outp + (size_t)row*ldo + col;
          *dst = f2bf(bf2f(*dst) + v + bias[col]);
        } else {
          ((float*)outp)[((size_t)kc*Mtot + row)*ldo + col] = v;
        }
      }
    }
  }
}

// ---------------- fused conv+SiLU+gate GEMM (per head, both gate pairs) ------------
// grid: (4 heads, Tci/128). Stages xh rows [m0-3, m0+132], computes xc in LDS,
// then p=0 GEMM on xc, p=1 GEMM on xh. B-fragments loaded direct from global (L2).
__global__ __launch_bounds__(256) void mfma_gate3(
    const u16* __restrict__ xh, const u16* __restrict__ Wg2,
    const float* __restrict__ cw, const float* __restrict__ cb,
    const float* __restrict__ gb, u16* __restrict__ gates, int Tci)
{
  __shared__ u16 xh_t[136*64];
  __shared__ u16 xc_t[128*64];
  const int tid = threadIdx.x;
  const int lane = tid & 63, wid = tid >> 6;
  const int fr = lane & 15, kb = lane >> 4;
  int nt, mt; swz_tile(nt, mt);
  const int hd = nt;
  const int m0 = mt*128;

  // stage xh rows m0-3 .. m0+132 (clamped) -> xh_t[136][64]
  for (int c = wid; c < 17; c += 4){
    int j = c*8 + (lane >> 3);
    int gr = m0 - 3 + j;
    gr = (gr < 0) ? 0 : ((gr >= Tci) ? Tci - 1 : gr);
    gload16(xh + (size_t)gr*DDIM + hd*64 + (lane & 7)*8, &xh_t[c*8*64]);
  }
  __syncthreads();

  // compute xc rows 0..127 (token m0+i), masked causal conv + SiLU
  {
    int e = tid & 63, ib = tid >> 6;
    int s0 = m0 % NS;
    float c0 = cw[0*DDIM + hd*64 + e];
    float c1 = cw[1*DDIM + hd*64 + e];
    float c2 = cw[2*DDIM + hd*64 + e];
    float c3 = cw[3*DDIM + hd*64 + e];
    float cbv = cb[hd*64 + e];
    #pragma unroll
    for (int ii = 0; ii < 32; ++ii){
      int i = ib + ii*4;
      int s = s0 + i;
      if (s >= NS) s -= NS;
      if (s >= NS) s -= NS;
      float a = cbv;
      if (s >= 3) a += bf2f(xh_t[(i+0)*64 + e]) * c0;
      if (s >= 2) a += bf2f(xh_t[(i+1)*64 + e]) * c1;
      if (s >= 1) a += bf2f(xh_t[(i+2)*64 + e]) * c2;
      a += bf2f(xh_t[(i+3)*64 + e]) * c3;
      xc_t[i*64 + e] = f2bf(a/(1.f + __expf(-a)));
    }
  }
  __syncthreads();

  // GEMM: wave -> p = wid>>1, row half = wid&1 (64 rows), cols 0..127 (NR=8)
  const int p = wid >> 1, half = wid & 1;
  const u16* Wmat = Wg2 + (size_t)(p*4 + hd)*8192;
  f32x4 acc[4][8];
  #pragma unroll
  for (int m=0;m<4;++m)
    #pragma unroll
    for (int n=0;n<8;++n) acc[m][n] = (f32x4){0.f,0.f,0.f,0.f};

  #pragma unroll
  for (int ks = 0; ks < 2; ++ks){
    int k0 = ks*32;
    bf16x8 af[4], wf[8];
    #pragma unroll
    for (int m=0;m<4;++m){
      int rl = half*64 + m*16 + fr;
      const u16* base = (p == 0) ? &xc_t[rl*64] : &xh_t[(rl+3)*64];
      af[m] = *(const bf16x8*)&base[k0 + kb*8];
    }
    #pragma unroll
    for (int n=0;n<8;++n)
      wf[n] = *(const bf16x8*)(Wmat + (size_t)(n*16 + fr)*64 + k0 + kb*8);
    #pragma unroll
    for (int m=0;m<4;++m)
      #pragma unroll
      for (int n=0;n<8;++n)
        acc[m][n] = __builtin_amdgcn_mfma_f32_16x16x32_bf16(af[m], wf[n], acc[m][n], 0,0,0);
  }
  #pragma unroll
  for (int m=0;m<4;++m){
    int rowb = m0 + half*64 + m*16 + kb*4;
    #pragma unroll
    for (int n=0;n<8;++n){
      int cl = n*16 + fr;
      int e = cl >> 1, gl = cl & 1;
      float bv = gb[(2*p + gl)*256 + hd*64 + e];
      int phys = hd*256 + p*128 + cl;
      #pragma unroll
      for (int r=0;r<4;++r)
        gates[(size_t)(rowb + r)*1024 + phys] = f2bf(acc[m][n][r] + bv);
    }
  }
}

// ---------------- FFN up + fast gelu*g2, BM=128 ------------------------------------
__global__ __launch_bounds__(256) void mfma_up_gelu4(
    const u16* __restrict__ A, const u16* __restrict__ Wt,
    const float* __restrict__ ub, u16* __restrict__ gp)
{
  __shared__ u16 As[2][128*32];
  __shared__ u16 Ws[2][128*32];
  const int tid = threadIdx.x;
  const int lane = tid & 63, wid = tid >> 6;
  const int fr = lane & 15, kb = lane >> 4;
  int nt, mt; swz_tile(nt, mt);
  const int m0 = mt*128, n0 = nt*64;
  const u16* W1 = Wt + (size_t)n0*256;
  const u16* W2 = Wt + (size_t)(384 + n0)*256;
  const int lrow = lane >> 2, lcol = (lane & 3)*8;

  auto stage = [&](int buf, int ks){
    int k0 = ks*32;
    for (int c = wid; c < 8; c += 4)
      gload16(A + (size_t)(m0 + c*16 + lrow)*256 + k0 + lcol, &As[buf][c*512]);
    for (int c = wid; c < 8; c += 4){
      const u16* src = (c < 4) ? (W1 + (size_t)(c*16 + lrow)*256)
                               : (W2 + (size_t)((c-4)*16 + lrow)*256);
      gload16(src + k0 + lcol, &Ws[buf][c*512]);
    }
  };

  f32x4 a1[2][4], a2[2][4];
  #pragma unroll
  for (int m=0;m<2;++m)
    #pragma unroll
    for (int n=0;n<4;++n){ a1[m][n]=(f32x4){0,0,0,0}; a2[m][n]=(f32x4){0,0,0,0}; }

  stage(0, 0);
  int cur = 0;
  #pragma unroll
  for (int ks = 0; ks < 8; ++ks){
    if (ks + 1 < 8){ stage(cur^1, ks+1); waitcnt_vm<4>(); }
    else waitcnt_vm<0>();
    __builtin_amdgcn_s_barrier();
    asm volatile("" ::: "memory");
    bf16x8 af[2], wf1[4], wf2[4];
    #pragma unroll
    for (int m=0;m<2;++m)
      af[m] = *(const bf16x8*)&As[cur][(wid*32 + m*16 + fr)*32 + kb*8];
    #pragma unroll
    for (int n=0;n<4;++n){
      wf1[n] = *(const bf16x8*)&Ws[cur][(n*16 + fr)*32 + kb*8];
      wf2[n] = *(const bf16x8*)&Ws[cur][(64 + n*16 + fr)*32 + kb*8];
    }
    #pragma unroll
    for (int m=0;m<2;++m)
      #pragma unroll
      for (int n=0;n<4;++n){
        a1[m][n] = __builtin_amdgcn_mfma_f32_16x16x32_bf16(af[m], wf1[n], a1[m][n], 0,0,0);
        a2[m][n] = __builtin_amdgcn_mfma_f32_16x16x32_bf16(af[m], wf2[n], a2[m][n], 0,0,0);
      }
    asm volatile("" ::: "memory");
    __builtin_amdgcn_s_barrier();
    cur ^= 1;
  }
  #pragma unroll
  for (int m=0;m<2;++m){
    int rowb = m0 + wid*32 + m*16 + kb*4;
    #pragma unroll
    for (int n=0;n<4;++n){
      int col = n0 + n*16 + fr;
      float b1 = ub[col], b2 = ub[384 + col];
      #pragma unroll
      for (int r=0;r<4;++r){
        float g1 = a1[m][n][r] + b1;
        float g2 = a2[m][n][r] + b2;
        float u  = 0.7978845608028654f*(g1 + 0.044715f*g1*g1*g1);
        float uc = fminf(fmaxf(u, -20.f), 20.f);
        float t2 = __expf(uc + uc);
        float th = (t2 - 1.f)/(t2 + 1.f);
        float ge = 0.5f*g1*(1.f + th);
        gp[(size_t)(rowb + r)*UPDIM + col] = f2bf(ge*g2);
      }
    }
  }
}

// ---------------- sLSTM scan v6: 2 seqs/block, 8 blocks/CU -------------------------
__global__ __launch_bounds__(256) void slstm_scan6(
    const u16* __restrict__ gates, const u16* __restrict__ Rgt,
    u16* __restrict__ y)
{
  __shared__ u16 h_lds[16*72];          // rows 0..1 live
  __shared__ float rec_lds[4][2][68];
  const int tid = threadIdx.x;
  const int w = tid >> 6, lane = tid & 63;
  const int hd = blockIdx.y, grp = blockIdx.x;
  const int fr = lane & 15, kb = lane >> 4;
  const int seq0 = grp*2;
  const u32* g32 = (const u32*)gates;

  bf16x8 bfr[4][2];
  {
    const u16* rb = Rgt + (size_t)(w*NHEAD + hd)*4096;
    #pragma unroll
    for (int n=0;n<4;++n)
      #pragma unroll
      for (int ks=0;ks<2;++ks)
        bfr[n][ks] = *(const bf16x8*)(rb + (size_t)(n*16 + fr)*64 + ks*32 + kb*8);
  }
  for (int i = tid; i < 16*72/2; i += 256) ((u32*)h_lds)[i] = 0u;
  float c = 0.f, nst = 0.f, m = 0.f;

  const int active = (w < 2);
  const size_t gb = active ? (((size_t)(seq0 + w)*NS)*512 + hd*128 + lane) : 0;
  u32 g0[2] = {0u,0u}, g1[2] = {0u,0u};
  if (active){
    g0[0] = g32[gb];        g0[1] = g32[gb + 64];
    g1[0] = g32[gb + 512];  g1[1] = g32[gb + 576];
  }
  __syncthreads();

  for (int s = 0; s < NS; ++s){
    u32 gn[2] = {0u, 0u};
    if (active && s + 2 < NS){
      size_t b2 = gb + (size_t)(s+2)*512;
      gn[0] = g32[b2];
      gn[1] = g32[b2 + 64];
    }
    bf16x8 af0 = *(const bf16x8*)&h_lds[fr*72 + kb*8];
    bf16x8 af1 = *(const bf16x8*)&h_lds[fr*72 + 32 + kb*8];
    f32x4 acc[4];
    #pragma unroll
    for (int n=0;n<4;++n){
      acc[n] = (f32x4){0,0,0,0};
      acc[n] = __builtin_amdgcn_mfma_f32_16x16x32_bf16(af0, bfr[n][0], acc[n], 0,0,0);
      acc[n] = __builtin_amdgcn_mfma_f32_16x16x32_bf16(af1, bfr[n][1], acc[n], 0,0,0);
    }
    if (kb == 0){
      #pragma unroll
      for (int n=0;n<4;++n){
        rec_lds[w][0][n*16 + fr] = acc[n][0];
        rec_lds[w][1][n*16 + fr] = acc[n][1];
      }
    }
    asm volatile("s_waitcnt lgkmcnt(0)" ::: "memory");
    __builtin_amdgcn_s_barrier();
    if (active){
      float ip = rec_lds[0][w][lane] + bf2f(g0[0] & 0xffffu);
      float fp = rec_lds[1][w][lane] + bf2f_hi(g0[0]);
      float zp = rec_lds[2][w][lane] + bf2f(g0[1] & 0xffffu);
      float op = rec_lds[3][w][lane] + bf2f_hi(g0[1]);
      float sp  = __logf(1.f + __expf(-fabsf(fp)));
      float lg  = m + fminf(fp, 0.f) - sp;
      float mn  = fmaxf(ip, lg);
      float iv  = __expf(ip - mn);
      float fv  = __expf(lg - mn);
      float zz  = fminf(fabsf(zp), 15.f);
      float t2  = __expf(zz + zz);
      float tha = (t2 - 1.f)/(t2 + 1.f);
      float th  = (zp >= 0.f) ? tha : -tha;
      c   = fv*c + iv*th;
      nst = fv*nst + iv;
      m   = mn;
      float hv = c * __builtin_amdgcn_rcpf(nst*(1.f + __expf(-op)));
      h_lds[w*72 + lane] = f2bf(hv);
      size_t t = (size_t)(seq0 + w)*NS + s;
      y[t*DDIM + hd*64 + lane] = f2bf(hv);
    }
    asm volatile("s_waitcnt lgkmcnt(0)" ::: "memory");
    __builtin_amdgcn_s_barrier();
    g0[0] = g1[0]; g0[1] = g1[1];
    g1[0] = gn[0]; g1[1] = gn[1];
  }
}

// ---------------- proj reduce over K-split slices ----------------------------------
__global__ __launch_bounds__(256) void proj_out(
    const float* __restrict__ ptmp, const float* __restrict__ bproj,
    float* __restrict__ out, int Nc, int n0glob){
  int gid = blockIdx.x*256 + threadIdx.x;
  if (gid >= Nc*PREDN) return;
  float acc = 0.f;
  #pragma unroll
  for (int kc = 0; kc < KC_PROJ; ++kc) acc += ptmp[(size_t)kc*Nc*PREDN + gid];
  int nl = gid / PREDN, j = gid - nl*PREDN;
  int n = n0glob + nl;
  out[((size_t)(n >> 5)*PREDN + j)*CCH + (n & 31)] = acc + bproj[j];
}

extern "C" void kernel_launch(void* const* d_in, const int* in_sizes, int n_in,
                              void* d_out, int out_size, void* d_ws, size_t ws_size,
                              hipStream_t stream) {
  const float* x      = (const float*)d_in[0];
  const float* W_emb  = (const float*)d_in[1];
  const float* b_emb  = (const float*)d_in[2];
  const float* ln1_w  = (const float*)d_in[3];
  const float* ln1_b  = (const float*)d_in[4];
  const float* conv_w = (const float*)d_in[5];
  const float* conv_b = (const float*)d_in[6];
  const float* Wg     = (const float*)d_in[7];
  const float* Rg     = (const float*)d_in[8];
  const float* gb     = (const float*)d_in[9];
  const float* gn_w   = (const float*)d_in[10];
  const float* ln2_w  = (const float*)d_in[11];
  const float* ln2_b  = (const float*)d_in[12];
  const float* up_w   = (const float*)d_in[13];
  const float* up_b   = (const float*)d_in[14];
  const float* dn_w   = (const float*)d_in[15];
  const float* dn_b   = (const float*)d_in[16];
  const float* post_w = (const float*)d_in[17];
  const float* post_b = (const float*)d_in[18];
  const float* W_proj = (const float*)d_in[19];
  const float* b_proj = (const float*)d_in[20];
  float* out = (float*)d_out;

  const size_t oWu   = 0;          // [2][768][256] bf16 : 1,572,864
  const size_t oWd   = 1572864;    // [2][256][384] bf16 :   786,432
  const size_t oWg2  = 2359296;    // [2][8][128][64] bf16 :  262,144
  const size_t oRgt  = 2621440;    // [2][16][64][64] bf16 :  524,288
  const size_t oWp   = 3145728;    // [96][16128] bf16 : 3,096,576
  const size_t oChunk = 6242304;
  const size_t per_seq = (size_t)3584*NS;   // 225,792 B
  int Nc = 0;
  const int cands[3] = {1024, 512, 256};
  for (int i = 0; i < 3; ++i)
    if (oChunk + (size_t)cands[i]*per_seq <= ws_size){ Nc = cands[i]; break; }
  if (Nc == 0) return;

  char* wsb = (char*)d_ws;
  u16* Wu   = (u16*)(wsb + oWu);
  u16* Wd   = (u16*)(wsb + oWd);
  u16* Wg2  = (u16*)(wsb + oWg2);
  u16* Rgt  = (u16*)(wsb + oRgt);
  u16* Wtp  = (u16*)(wsb + oWp);

  for (int blk = 0; blk < 2; ++blk){
    cvt_transpose_t<<<dim3(8, 24), 256, 0, stream>>>(
        up_w + (size_t)blk*256*768, Wu + (size_t)blk*768*256, 256, 768);
    cvt_transpose_t<<<dim3(12, 8), 256, 0, stream>>>(
        dn_w + (size_t)blk*384*256, Wd + (size_t)blk*256*384, 384, 256);
  }
  cvt_gateW2<<<16, 256, 0, stream>>>(Wg, Wg2);
  cvt_gate<<<32, 256, 0, stream>>>(Rg, Rgt);
  cvt_transpose_t<<<dim3(504, 3), 256, 0, stream>>>(W_proj, Wtp, 16128, 96);

  for (int n0 = 0; n0 < NSEQ; n0 += Nc){
    const int    nc  = (NSEQ - n0 < Nc) ? (NSEQ - n0) : Nc;
    const size_t Tc  = (size_t)nc * NS;
    char* cb = wsb + oChunk;
    u16*   h_c   = (u16*)cb;                          // Tc*512 B
    u16*   bufA  = (u16*)(cb + Tc*512);               // Tc*512 B
    u16*   bufB  = (u16*)(cb + Tc*1024);              // Tc*512 B (scan y out)
    u16*   gates = (u16*)(cb + Tc*1536);              // Tc*2048 B
    u16*   gp    = gates;                             // reuse (Tc*768 B)
    float* ptmp  = (float*)(cb + Tc*1536 + Tc*1024);  // overlay in gates tail
    const int t_base = n0*NS;
    const int Tci = (int)Tc;

    patch_embed_ln_v<<<Tci/4, 256, 0, stream>>>(
        x, W_emb, b_emb, ln1_w, ln1_b, h_c, bufA, t_base);

    for (int blk = 0; blk < 2; ++blk){
      if (blk == 1)
        layernorm_v<<<Tci/4, 256, 0, stream>>>(h_c, ln1_w + DDIM, ln1_b + DDIM, bufA);
      mfma_gate3<<<dim3(4, Tci/128), 256, 0, stream>>>(
          bufA, Wg2 + (size_t)blk*8*8192, conv_w + blk*4*DDIM, conv_b + blk*DDIM,
          gb + blk*4*DDIM, gates, Tci);
      slstm_scan6<<<dim3(nc/2, NHEAD), 256, 0, stream>>>(
          gates, Rgt + (size_t)blk*16*4096, bufB);
      gn_res_ln_v<<<Tci/4, 256, 0, stream>>>(
          bufB, gn_w + blk*DDIM, ln2_w + blk*DDIM, ln2_b + blk*DDIM, h_c, bufA);
      mfma_up_gelu4<<<dim3(6, Tci/128), 256, 0, stream>>>(
          bufA, Wu + (size_t)blk*768*256, up_b + blk*2*UPDIM, gp);
      mfma_gemm2<128,128,2,2,4,4,1,4><<<dim3(2, Tci/128), 256, 0, stream>>>(
          gp, UPDIM, Wd + (size_t)blk*256*384, UPDIM,
          dn_b + blk*DDIM, (void*)h_c, DDIM, 12, 0, 0);
    }

    layernorm_v<<<Tci/4, 256, 0, stream>>>(h_c, post_w, post_b, bufA);
    mfma_gemm2<64,96,2,2,2,3,2,0><<<dim3(1, nc/64, KC_PROJ), 256, 0, stream>>>(
        bufA, NS*DDIM, Wtp, NS*DDIM,
        b_proj, (void*)ptmp, PREDN, KCHUNK_PROJ/32, KCHUNK_PROJ, nc);
    proj_out<<<(nc*PREDN + 255)/256, 256, 0, stream>>>(ptmp, b_proj, out, nc, n0);
  }
}

// Round 17
// 638.341 us; speedup vs baseline: 1.1827x; 1.1827x over previous
//
#include <hip/hip_runtime.h>
#include <stdint.h>

typedef unsigned short u16;
typedef unsigned int   u32;
typedef __attribute__((ext_vector_type(8))) short bf16x8;
typedef __attribute__((ext_vector_type(4))) float f32x4;

#define NS      63
#define NSEQ    1024
#define DDIM    256
#define NHEAD   4
#define DHEAD   64
#define UPDIM   384
#define PREDN   96
#define LLEN    512
#define CCH     32
#define PSIZE   16
#define PSTRIDE 8
#define KC_PROJ 28
#define KCHUNK_PROJ 576

__device__ __forceinline__ float bf2f(u32 lo16){
  union { u32 i; float f; } v; v.i = lo16 << 16; return v.f;
}
__device__ __forceinline__ float bf2f_hi(u32 u){
  union { u32 i; float f; } v; v.i = u & 0xffff0000u; return v.f;
}
__device__ __forceinline__ u16 f2bf(float f){
  union { u32 i; float f; } v; v.f = f;
  u32 u = v.i; u += 0x7fffu + ((u >> 16) & 1u);
  return (u16)(u >> 16);
}

__device__ __forceinline__ void gload16(const u16* g, u16* lds){
  __builtin_amdgcn_global_load_lds(
      (const __attribute__((address_space(1))) u32*)g,
      (__attribute__((address_space(3))) u32*)lds, 16, 0, 0);
}

template<int N> __device__ __forceinline__ void waitcnt_vm(){
  if constexpr (N == 0) asm volatile("s_waitcnt vmcnt(0)" ::: "memory");
  else if constexpr (N == 4) asm volatile("s_waitcnt vmcnt(4)" ::: "memory");
  else if constexpr (N == 6) asm volatile("s_waitcnt vmcnt(6)" ::: "memory");
}

// bijective XCD swizzle (m204)
__device__ __forceinline__ void swz_tile(int &nt, int &mt){
  int gx = gridDim.x, gy = gridDim.y;
  int nwg = gx*gy;
  int flat = blockIdx.y*gx + blockIdx.x;
  int c = flat & 7, s = flat >> 3;
  int q = nwg >> 3, r = nwg & 7;
  int base = c*q + (c < r ? c : r);
  int t = base + s;
  nt = t % gx; mt = t / gx;
}

// ---------------- LDS-tiled transpose: dst[c][r] = bf16(src[r][c]) -----------------
__global__ __launch_bounds__(256) void cvt_transpose_t(
    const float* __restrict__ src, u16* __restrict__ dst, int R, int C){
  __shared__ u16 tile[32][33];
  int rb = blockIdx.x*32, cb = blockIdx.y*32;
  int tx = threadIdx.x & 31, ty = threadIdx.x >> 5;
  #pragma unroll
  for (int i = ty; i < 32; i += 8){
    int r = rb + i, c = cb + tx;
    tile[i][tx] = (r < R && c < C) ? f2bf(src[(size_t)r*C + c]) : (u16)0;
  }
  __syncthreads();
  #pragma unroll
  for (int i = ty; i < 32; i += 8){
    int c = cb + i, r = rb + tx;
    if (c < C && r < R) dst[(size_t)c*R + r] = tile[tx][i];
  }
}

__global__ __launch_bounds__(256) void cvt_gate(
    const float* __restrict__ src, u16* __restrict__ dst){
  int mat = blockIdx.x, t = threadIdx.x;
  const float* s = src + (size_t)mat*4096;
  u16* d = dst + (size_t)mat*4096;
  for (int i = t; i < 4096; i += 256){
    int r = i >> 6, c = i & 63;
    d[c*64 + r] = f2bf(s[i]);
  }
}

// gate weight true-K layout, col order n = e*2+gl: dst[(blk*2+p)*4+hd][n][k]
__global__ __launch_bounds__(256) void cvt_gateW2(
    const float* __restrict__ Wg, u16* __restrict__ dst){
  int mi = blockIdx.x;
  int blk = mi >> 3, p = (mi >> 2) & 1, hd = mi & 3;
  u16* d = dst + (size_t)mi*8192;
  for (int i = threadIdx.x; i < 8192; i += 256){
    int n = i >> 6, k = i & 63;
    int e = n >> 1, gl = n & 1;
    int g = 2*p + gl;
    d[i] = f2bf(Wg[((((size_t)blk*4 + g)*4 + hd)*64 + k)*64 + e]);
  }
}

// ---------------- patch embedding + ln1(blk0), wave = token, vectorized ------------
__global__ __launch_bounds__(256) void patch_embed_ln_v(
    const float* __restrict__ x, const float* __restrict__ Wemb,
    const float* __restrict__ bemb, const float* __restrict__ w1,
    const float* __restrict__ b1, u16* __restrict__ h,
    u16* __restrict__ outA, int t_base){
  int wv = blockIdx.x*4 + (threadIdx.x >> 6);
  int lane = threadIdx.x & 63;
  int tg = t_base + wv;
  int n = tg / NS, s = tg - n*NS;
  int b = n >> 5, c = n & 31;
  int l0 = s * PSTRIDE;
  float4 acc = *(const float4*)(bemb + lane*4);
  #pragma unroll
  for (int p = 0; p < PSIZE; ++p){
    float xv = x[((size_t)b*LLEN + l0 + p)*CCH + c];
    float4 we = *(const float4*)(Wemb + p*DDIM + lane*4);
    acc.x += xv*we.x; acc.y += xv*we.y; acc.z += xv*we.z; acc.w += xv*we.w;
  }
  ushort4 hu; hu.x=f2bf(acc.x); hu.y=f2bf(acc.y); hu.z=f2bf(acc.z); hu.w=f2bf(acc.w);
  *(ushort4*)(h + (size_t)wv*DDIM + lane*4) = hu;
  float s1 = acc.x+acc.y+acc.z+acc.w;
  float s2 = acc.x*acc.x+acc.y*acc.y+acc.z*acc.z+acc.w*acc.w;
  #pragma unroll
  for (int o = 1; o < 64; o <<= 1){ s1 += __shfl_xor(s1,o,64); s2 += __shfl_xor(s2,o,64); }
  float mu = s1*(1.f/DDIM);
  float var = s2*(1.f/DDIM) - mu*mu;
  float rstd = rsqrtf(var + 1e-5f);
  float4 wf = *(const float4*)(w1 + lane*4);
  float4 bf = *(const float4*)(b1 + lane*4);
  ushort4 o4;
  o4.x = f2bf((acc.x-mu)*rstd*wf.x + bf.x);
  o4.y = f2bf((acc.y-mu)*rstd*wf.y + bf.y);
  o4.z = f2bf((acc.z-mu)*rstd*wf.z + bf.z);
  o4.w = f2bf((acc.w-mu)*rstd*wf.w + bf.w);
  *(ushort4*)(outA + (size_t)wv*DDIM + lane*4) = o4;
}

// ---------------- layernorm, wave = token, vectorized ------------------------------
__global__ __launch_bounds__(256) void layernorm_v(
    const u16* __restrict__ in, const float* __restrict__ w,
    const float* __restrict__ b, u16* __restrict__ out){
  int wv = blockIdx.x*4 + (threadIdx.x >> 6);
  int lane = threadIdx.x & 63;
  ushort4 u = *(const ushort4*)(in + (size_t)wv*DDIM + lane*4);
  float v0=bf2f(u.x), v1=bf2f(u.y), v2=bf2f(u.z), v3=bf2f(u.w);
  float s1 = v0+v1+v2+v3, s2 = v0*v0+v1*v1+v2*v2+v3*v3;
  #pragma unroll
  for (int o = 1; o < 64; o <<= 1){ s1 += __shfl_xor(s1,o,64); s2 += __shfl_xor(s2,o,64); }
  float mu = s1*(1.f/DDIM);
  float var = s2*(1.f/DDIM) - mu*mu;
  float rstd = rsqrtf(var + 1e-5f);
  float4 wf = *(const float4*)(w + lane*4);
  float4 bf = *(const float4*)(b + lane*4);
  ushort4 o4;
  o4.x = f2bf((v0-mu)*rstd*wf.x + bf.x);
  o4.y = f2bf((v1-mu)*rstd*wf.y + bf.y);
  o4.z = f2bf((v2-mu)*rstd*wf.z + bf.z);
  o4.w = f2bf((v3-mu)*rstd*wf.w + bf.w);
  *(ushort4*)(out + (size_t)wv*DDIM + lane*4) = o4;
}

// ---------------- fused groupnorm + residual + layernorm, vectorized ---------------
__global__ __launch_bounds__(256) void gn_res_ln_v(
    const u16* __restrict__ y, const float* __restrict__ gnw,
    const float* __restrict__ w2, const float* __restrict__ b2,
    u16* __restrict__ h, u16* __restrict__ outA){
  int wv = blockIdx.x*4 + (threadIdx.x >> 6);
  int lane = threadIdx.x & 63;
  ushort4 u = *(const ushort4*)(y + (size_t)wv*DDIM + lane*4);
  float v0=bf2f(u.x), v1=bf2f(u.y), v2=bf2f(u.z), v3=bf2f(u.w);
  float s1 = v0+v1+v2+v3, s2 = v0*v0+v1*v1+v2*v2+v3*v3;
  #pragma unroll
  for (int o = 1; o < 16; o <<= 1){ s1 += __shfl_xor(s1,o,64); s2 += __shfl_xor(s2,o,64); }
  float mu64 = s1*(1.f/64.f);
  float var64 = s2*(1.f/64.f) - mu64*mu64;
  float rstd64 = rsqrtf(var64 + 1e-5f);
  float4 gw = *(const float4*)(gnw + lane*4);
  ushort4 hu = *(const ushort4*)(h + (size_t)wv*DDIM + lane*4);
  float h0 = bf2f(hu.x) + (v0-mu64)*rstd64*gw.x;
  float h1 = bf2f(hu.y) + (v1-mu64)*rstd64*gw.y;
  float h2 = bf2f(hu.z) + (v2-mu64)*rstd64*gw.z;
  float h3 = bf2f(hu.w) + (v3-mu64)*rstd64*gw.w;
  ushort4 hn; hn.x=f2bf(h0); hn.y=f2bf(h1); hn.z=f2bf(h2); hn.w=f2bf(h3);
  *(ushort4*)(h + (size_t)wv*DDIM + lane*4) = hn;
  float t1 = h0+h1+h2+h3, t2 = h0*h0+h1*h1+h2*h2+h3*h3;
  #pragma unroll
  for (int o = 1; o < 64; o <<= 1){ t1 += __shfl_xor(t1,o,64); t2 += __shfl_xor(t2,o,64); }
  float mu = t1*(1.f/DDIM);
  float var = t2*(1.f/DDIM) - mu*mu;
  float rstd = rsqrtf(var + 1e-5f);
  float4 wf = *(const float4*)(w2 + lane*4);
  float4 bf = *(const float4*)(b2 + lane*4);
  ushort4 o4;
  o4.x = f2bf((h0-mu)*rstd*wf.x + bf.x);
  o4.y = f2bf((h1-mu)*rstd*wf.y + bf.y);
  o4.z = f2bf((h2-mu)*rstd*wf.z + bf.z);
  o4.w = f2bf((h3-mu)*rstd*wf.w + bf.w);
  *(ushort4*)(outA + (size_t)wv*DDIM + lane*4) = o4;
}

// ---------------- causal depthwise conv K=4 + SiLU, vectorized ---------------------
__global__ __launch_bounds__(256) void conv_silu_v(
    const u16* __restrict__ xln, const float* __restrict__ cw,
    const float* __restrict__ cb, u16* __restrict__ xc){
  int wv = blockIdx.x*4 + (threadIdx.x >> 6);
  int lane = threadIdx.x & 63;
  int s = wv % NS;
  float4 acc = *(const float4*)(cb + lane*4);
  #pragma unroll
  for (int k = 0; k < 4; ++k){
    int ss = s + k - 3;
    if (ss >= 0){
      ushort4 xu = *(const ushort4*)(xln + (size_t)(wv + k - 3)*DDIM + lane*4);
      float4 cv = *(const float4*)(cw + k*DDIM + lane*4);
      acc.x += bf2f(xu.x)*cv.x; acc.y += bf2f(xu.y)*cv.y;
      acc.z += bf2f(xu.z)*cv.z; acc.w += bf2f(xu.w)*cv.w;
    }
  }
  ushort4 o4;
  o4.x = f2bf(acc.x/(1.f + __expf(-acc.x)));
  o4.y = f2bf(acc.y/(1.f + __expf(-acc.y)));
  o4.z = f2bf(acc.z/(1.f + __expf(-acc.z)));
  o4.w = f2bf(acc.w/(1.f + __expf(-acc.w)));
  *(ushort4*)(xc + (size_t)wv*DDIM + lane*4) = o4;
}

// ---------------- generic MFMA GEMM (XCD-swizzled) ---------------------------------
template<int BM,int BN,int WR,int WC,int MR,int NR,int MODE,int VM>
__global__ __launch_bounds__(256) void mfma_gemm2(
    const u16* __restrict__ A, int lda,
    const u16* __restrict__ Wt, int ldwt,
    const float* __restrict__ bias, void* __restrict__ outp, int ldo,
    int ksteps, int kchunk, int Mtot)
{
  constexpr int nA = BM/16, nW = BN/16;
  __shared__ u16 As[2][BM*32];
  __shared__ u16 Ws[2][BN*32];
  const int tid = threadIdx.x;
  const int lane = tid & 63, wid = tid >> 6;
  const int wr = wid / WC, wc = wid % WC;
  const int fr = lane & 15, kb = lane >> 4;
  int nt, mt; swz_tile(nt, mt);
  const int m0 = mt*BM, n0 = nt*BN;
  const int kc = blockIdx.z;
  const int kbeg = kc*kchunk;
  const u16* Ab = A + (size_t)m0*lda + kbeg;
  const u16* Wb = Wt + (size_t)n0*ldwt + kbeg;
  const int lrow = lane >> 2, lcol = (lane & 3)*8;

  auto stage = [&](int buf, int ks){
    int k0 = ks*32;
    for (int c = wid; c < nA; c += 4)
      gload16(Ab + (size_t)(c*16 + lrow)*lda + k0 + lcol, &As[buf][c*512]);
    for (int c = wid; c < nW; c += 4)
      gload16(Wb + (size_t)(c*16 + lrow)*ldwt + k0 + lcol, &Ws[buf][c*512]);
  };

  f32x4 acc[MR][NR];
  #pragma unroll
  for (int m=0;m<MR;++m)
    #pragma unroll
    for (int n=0;n<NR;++n) acc[m][n] = (f32x4){0.f,0.f,0.f,0.f};

  stage(0, 0);
  if (VM == 0) __syncthreads();
  int cur = 0;
  for (int ks = 0; ks < ksteps; ++ks){
    if (VM == 0){
      if (ks + 1 < ksteps) stage(cur^1, ks+1);
    } else {
      if (ks + 1 < ksteps){ stage(cur^1, ks+1); waitcnt_vm<VM>(); }
      else waitcnt_vm<0>();
      __builtin_amdgcn_s_barrier();
      asm volatile("" ::: "memory");
    }
    bf16x8 af[MR], wf[NR];
    #pragma unroll
    for (int m=0;m<MR;++m)
      af[m] = *(const bf16x8*)&As[cur][(wr*MR*16 + m*16 + fr)*32 + kb*8];
    #pragma unroll
    for (int n=0;n<NR;++n)
      wf[n] = *(const bf16x8*)&Ws[cur][(wc*NR*16 + n*16 + fr)*32 + kb*8];
    #pragma unroll
    for (int m=0;m<MR;++m)
      #pragma unroll
      for (int n=0;n<NR;++n)
        acc[m][n] = __builtin_amdgcn_mfma_f32_16x16x32_bf16(af[m], wf[n], acc[m][n], 0,0,0);
    if (VM == 0){
      __syncthreads();
    } else {
      asm volatile("" ::: "memory");
      __builtin_amdgcn_s_barrier();
    }
    cur ^= 1;
  }
  #pragma unroll
  for (int m=0;m<MR;++m){
    int rowb = m0 + wr*MR*16 + m*16 + kb*4;
    #pragma unroll
    for (int n=0;n<NR;++n){
      int col = n0 + wc*NR*16 + n*16 + fr;
      #pragma unroll
      for (int r=0;r<4;++r){
        int row = rowb + r;
        float v = acc[m][n][r];
        if (MODE == 1){
          u16* dst = (u16*)outp + (size_t)row*ldo + col;
          *dst = f2bf(bf2f(*dst) + v + bias[col]);
        } else {
          ((float*)outp)[((size_t)kc*Mtot + row)*ldo + col] = v;
        }
      }
    }
  }
}

// ---------------- gate GEMM, true K=64 ---------------------------------------------
__global__ __launch_bounds__(256) void mfma_gate2(
    const u16* __restrict__ xc, const u16* __restrict__ xh,
    const u16* __restrict__ Wg2, const float* __restrict__ gb,
    u16* __restrict__ gates)
{
  __shared__ u16 As[2][128*32];
  __shared__ u16 Ws[2][128*32];
  const int tid = threadIdx.x;
  const int lane = tid & 63, wid = tid >> 6;
  const int wr = wid >> 1, wc = wid & 1;
  const int fr = lane & 15, kb = lane >> 4;
  int nt, mt; swz_tile(nt, mt);
  const int p = nt >> 2, hd = nt & 3;
  const int m0 = mt*128;
  const u16* Ain = (p == 0) ? xc : xh;
  const u16* Wb = Wg2 + (size_t)nt*8192;
  const int lrow = lane >> 2, lcol = (lane & 3)*8;

  auto stage = [&](int buf, int ks){
    int k0 = ks*32;
    for (int c = wid; c < 8; c += 4)
      gload16(Ain + (size_t)(m0 + c*16 + lrow)*DDIM + hd*64 + k0 + lcol, &As[buf][c*512]);
    for (int c = wid; c < 8; c += 4)
      gload16(Wb + (size_t)(c*16 + lrow)*64 + k0 + lcol, &Ws[buf][c*512]);
  };

  f32x4 acc[4][4];
  #pragma unroll
  for (int m=0;m<4;++m)
    #pragma unroll
    for (int n=0;n<4;++n) acc[m][n] = (f32x4){0.f,0.f,0.f,0.f};

  stage(0, 0);
  int cur = 0;
  #pragma unroll
  for (int ks = 0; ks < 2; ++ks){
    if (ks == 0){ stage(1, 1); waitcnt_vm<4>(); }
    else waitcnt_vm<0>();
    __builtin_amdgcn_s_barrier();
    asm volatile("" ::: "memory");
    bf16x8 af[4], wf[4];
    #pragma unroll
    for (int m=0;m<4;++m)
      af[m] = *(const bf16x8*)&As[cur][(wr*64 + m*16 + fr)*32 + kb*8];
    #pragma unroll
    for (int n=0;n<4;++n)
      wf[n] = *(const bf16x8*)&Ws[cur][(wc*64 + n*16 + fr)*32 + kb*8];
    #pragma unroll
    for (int m=0;m<4;++m)
      #pragma unroll
      for (int n=0;n<4;++n)
        acc[m][n] = __builtin_amdgcn_mfma_f32_16x16x32_bf16(af[m], wf[n], acc[m][n], 0,0,0);
    asm volatile("" ::: "memory");
    __builtin_amdgcn_s_barrier();
    cur ^= 1;
  }
  #pragma unroll
  for (int m=0;m<4;++m){
    int rowb = m0 + wr*64 + m*16 + kb*4;
    #pragma unroll
    for (int n=0;n<4;++n){
      int cl = wc*64 + n*16 + fr;
      int e = cl >> 1, gl = cl & 1;
      float bv = gb[(2*p + gl)*256 + hd*64 + e];
      int phys = hd*256 + p*128 + cl;
      #pragma unroll
      for (int r=0;r<4;++r)
        gates[(size_t)(rowb + r)*1024 + phys] = f2bf(acc[m][n][r] + bv);
    }
  }
}

// ---------------- FFN up + fast gelu*g2, BM=128 ------------------------------------
__global__ __launch_bounds__(256) void mfma_up_gelu4(
    const u16* __restrict__ A, const u16* __restrict__ Wt,
    const float* __restrict__ ub, u16* __restrict__ gp)
{
  __shared__ u16 As[2][128*32];
  __shared__ u16 Ws[2][128*32];
  const int tid = threadIdx.x;
  const int lane = tid & 63, wid = tid >> 6;
  const int fr = lane & 15, kb = lane >> 4;
  int nt, mt; swz_tile(nt, mt);
  const int m0 = mt*128, n0 = nt*64;
  const u16* W1 = Wt + (size_t)n0*256;
  const u16* W2 = Wt + (size_t)(384 + n0)*256;
  const int lrow = lane >> 2, lcol = (lane & 3)*8;

  auto stage = [&](int buf, int ks){
    int k0 = ks*32;
    for (int c = wid; c < 8; c += 4)
      gload16(A + (size_t)(m0 + c*16 + lrow)*256 + k0 + lcol, &As[buf][c*512]);
    for (int c = wid; c < 8; c += 4){
      const u16* src = (c < 4) ? (W1 + (size_t)(c*16 + lrow)*256)
                               : (W2 + (size_t)((c-4)*16 + lrow)*256);
      gload16(src + k0 + lcol, &Ws[buf][c*512]);
    }
  };

  f32x4 a1[2][4], a2[2][4];
  #pragma unroll
  for (int m=0;m<2;++m)
    #pragma unroll
    for (int n=0;n<4;++n){ a1[m][n]=(f32x4){0,0,0,0}; a2[m][n]=(f32x4){0,0,0,0}; }

  stage(0, 0);
  int cur = 0;
  #pragma unroll
  for (int ks = 0; ks < 8; ++ks){
    if (ks + 1 < 8){ stage(cur^1, ks+1); waitcnt_vm<4>(); }
    else waitcnt_vm<0>();
    __builtin_amdgcn_s_barrier();
    asm volatile("" ::: "memory");
    bf16x8 af[2], wf1[4], wf2[4];
    #pragma unroll
    for (int m=0;m<2;++m)
      af[m] = *(const bf16x8*)&As[cur][(wid*32 + m*16 + fr)*32 + kb*8];
    #pragma unroll
    for (int n=0;n<4;++n){
      wf1[n] = *(const bf16x8*)&Ws[cur][(n*16 + fr)*32 + kb*8];
      wf2[n] = *(const bf16x8*)&Ws[cur][(64 + n*16 + fr)*32 + kb*8];
    }
    #pragma unroll
    for (int m=0;m<2;++m)
      #pragma unroll
      for (int n=0;n<4;++n){
        a1[m][n] = __builtin_amdgcn_mfma_f32_16x16x32_bf16(af[m], wf1[n], a1[m][n], 0,0,0);
        a2[m][n] = __builtin_amdgcn_mfma_f32_16x16x32_bf16(af[m], wf2[n], a2[m][n], 0,0,0);
      }
    asm volatile("" ::: "memory");
    __builtin_amdgcn_s_barrier();
    cur ^= 1;
  }
  #pragma unroll
  for (int m=0;m<2;++m){
    int rowb = m0 + wid*32 + m*16 + kb*4;
    #pragma unroll
    for (int n=0;n<4;++n){
      int col = n0 + n*16 + fr;
      float b1 = ub[col], b2 = ub[384 + col];
      #pragma unroll
      for (int r=0;r<4;++r){
        float g1 = a1[m][n][r] + b1;
        float g2 = a2[m][n][r] + b2;
        float u  = 0.7978845608028654f*(g1 + 0.044715f*g1*g1*g1);
        float uc = fminf(fmaxf(u, -20.f), 20.f);
        float t2 = __expf(uc + uc);
        float th = (t2 - 1.f)/(t2 + 1.f);
        float ge = 0.5f*g1*(1.f + th);
        gp[(size_t)(rowb + r)*UPDIM + col] = f2bf(ge*g2);
      }
    }
  }
}

// ---------------- sLSTM scan v5: 4 seqs/block, 4 blocks/CU -------------------------
__global__ __launch_bounds__(256) void slstm_scan5(
    const u16* __restrict__ gates, const u16* __restrict__ Rgt,
    u16* __restrict__ y)
{
  __shared__ u16 h_lds[16*72];
  __shared__ float rec_lds[4][4][68];
  const int tid = threadIdx.x;
  const int w = tid >> 6, lane = tid & 63;
  const int hd = blockIdx.y, grp = blockIdx.x;
  const int fr = lane & 15, kb = lane >> 4;
  const int seq0 = grp*4;
  const u32* g32 = (const u32*)gates;

  bf16x8 bfr[4][2];
  {
    const u16* rb = Rgt + (size_t)(w*NHEAD + hd)*4096;
    #pragma unroll
    for (int n=0;n<4;++n)
      #pragma unroll
      for (int ks=0;ks<2;++ks)
        bfr[n][ks] = *(const bf16x8*)(rb + (size_t)(n*16 + fr)*64 + ks*32 + kb*8);
  }
  for (int i = tid; i < 16*72/2; i += 256) ((u32*)h_lds)[i] = 0u;
  float c = 0.f, nst = 0.f, m = 0.f;

  const size_t gb = ((size_t)(seq0 + w)*NS)*512 + hd*128 + lane;
  u32 g0[2], g1[2];
  g0[0] = g32[gb];        g0[1] = g32[gb + 64];
  g1[0] = g32[gb + 512];  g1[1] = g32[gb + 576];
  __syncthreads();

  for (int s = 0; s < NS; ++s){
    u32 gn[2] = {0u, 0u};
    if (s + 2 < NS){
      size_t b2 = gb + (size_t)(s+2)*512;
      gn[0] = g32[b2];
      gn[1] = g32[b2 + 64];
    }
    bf16x8 af0 = *(const bf16x8*)&h_lds[fr*72 + kb*8];
    bf16x8 af1 = *(const bf16x8*)&h_lds[fr*72 + 32 + kb*8];
    f32x4 acc[4];
    #pragma unroll
    for (int n=0;n<4;++n){
      acc[n] = (f32x4){0,0,0,0};
      acc[n] = __builtin_amdgcn_mfma_f32_16x16x32_bf16(af0, bfr[n][0], acc[n], 0,0,0);
      acc[n] = __builtin_amdgcn_mfma_f32_16x16x32_bf16(af1, bfr[n][1], acc[n], 0,0,0);
    }
    if (kb == 0){
      #pragma unroll
      for (int n=0;n<4;++n)
        #pragma unroll
        for (int r=0;r<4;++r)
          rec_lds[w][r][n*16 + fr] = acc[n][r];
    }
    asm volatile("s_waitcnt lgkmcnt(0)" ::: "memory");
    __builtin_amdgcn_s_barrier();
    {
      float ip = rec_lds[0][w][lane] + bf2f(g0[0] & 0xffffu);
      float fp = rec_lds[1][w][lane] + bf2f_hi(g0[0]);
      float zp = rec_lds[2][w][lane] + bf2f(g0[1] & 0xffffu);
      float op = rec_lds[3][w][lane] + bf2f_hi(g0[1]);
      float sp  = __logf(1.f + __expf(-fabsf(fp)));
      float lg  = m + fminf(fp, 0.f) - sp;
      float mn  = fmaxf(ip, lg);
      float iv  = __expf(ip - mn);
      float fv  = __expf(lg - mn);
      float zz  = fminf(fabsf(zp), 15.f);
      float t2  = __expf(zz + zz);
      float tha = (t2 - 1.f)/(t2 + 1.f);
      float th  = (zp >= 0.f) ? tha : -tha;
      c   = fv*c + iv*th;
      nst = fv*nst + iv;
      m   = mn;
      float hv = c * __builtin_amdgcn_rcpf(nst*(1.f + __expf(-op)));
      h_lds[w*72 + lane] = f2bf(hv);
      size_t t = (size_t)(seq0 + w)*NS + s;
      y[t*DDIM + hd*64 + lane] = f2bf(hv);
    }
    asm volatile("s_waitcnt lgkmcnt(0)" ::: "memory");
    __builtin_amdgcn_s_barrier();
    g0[0] = g1[0]; g0[1] = g1[1];
    g1[0] = gn[0]; g1[1] = gn[1];
  }
}

// ---------------- proj reduce over K-split slices ----------------------------------
__global__ __launch_bounds__(256) void proj_out(
    const float* __restrict__ ptmp, const float* __restrict__ bproj,
    float* __restrict__ out, int Nc, int n0glob){
  int gid = blockIdx.x*256 + threadIdx.x;
  if (gid >= Nc*PREDN) return;
  float acc = 0.f;
  #pragma unroll
  for (int kc = 0; kc < KC_PROJ; ++kc) acc += ptmp[(size_t)kc*Nc*PREDN + gid];
  int nl = gid / PREDN, j = gid - nl*PREDN;
  int n = n0glob + nl;
  out[((size_t)(n >> 5)*PREDN + j)*CCH + (n & 31)] = acc + bproj[j];
}

extern "C" void kernel_launch(void* const* d_in, const int* in_sizes, int n_in,
                              void* d_out, int out_size, void* d_ws, size_t ws_size,
                              hipStream_t stream) {
  const float* x      = (const float*)d_in[0];
  const float* W_emb  = (const float*)d_in[1];
  const float* b_emb  = (const float*)d_in[2];
  const float* ln1_w  = (const float*)d_in[3];
  const float* ln1_b  = (const float*)d_in[4];
  const float* conv_w = (const float*)d_in[5];
  const float* conv_b = (const float*)d_in[6];
  const float* Wg     = (const float*)d_in[7];
  const float* Rg     = (const float*)d_in[8];
  const float* gb     = (const float*)d_in[9];
  const float* gn_w   = (const float*)d_in[10];
  const float* ln2_w  = (const float*)d_in[11];
  const float* ln2_b  = (const float*)d_in[12];
  const float* up_w   = (const float*)d_in[13];
  const float* up_b   = (const float*)d_in[14];
  const float* dn_w   = (const float*)d_in[15];
  const float* dn_b   = (const float*)d_in[16];
  const float* post_w = (const float*)d_in[17];
  const float* post_b = (const float*)d_in[18];
  const float* W_proj = (const float*)d_in[19];
  const float* b_proj = (const float*)d_in[20];
  float* out = (float*)d_out;

  const size_t oWu   = 0;          // [2][768][256] bf16 : 1,572,864
  const size_t oWd   = 1572864;    // [2][256][384] bf16 :   786,432
  const size_t oWg2  = 2359296;    // [2][8][128][64] bf16 :  262,144
  const size_t oRgt  = 2621440;    // [2][16][64][64] bf16 :  524,288
  const size_t oWp   = 3145728;    // [96][16128] bf16 : 3,096,576
  const size_t oChunk = 6242304;
  const size_t per_seq = (size_t)3584*NS;   // 225,792 B
  int Nc = 0;
  const int cands[3] = {1024, 512, 256};
  for (int i = 0; i < 3; ++i)
    if (oChunk + (size_t)cands[i]*per_seq <= ws_size){ Nc = cands[i]; break; }
  if (Nc == 0) return;

  char* wsb = (char*)d_ws;
  u16* Wu   = (u16*)(wsb + oWu);
  u16* Wd   = (u16*)(wsb + oWd);
  u16* Wg2  = (u16*)(wsb + oWg2);
  u16* Rgt  = (u16*)(wsb + oRgt);
  u16* Wtp  = (u16*)(wsb + oWp);

  for (int blk = 0; blk < 2; ++blk){
    cvt_transpose_t<<<dim3(8, 24), 256, 0, stream>>>(
        up_w + (size_t)blk*256*768, Wu + (size_t)blk*768*256, 256, 768);
    cvt_transpose_t<<<dim3(12, 8), 256, 0, stream>>>(
        dn_w + (size_t)blk*384*256, Wd + (size_t)blk*256*384, 384, 256);
  }
  cvt_gateW2<<<16, 256, 0, stream>>>(Wg, Wg2);
  cvt_gate<<<32, 256, 0, stream>>>(Rg, Rgt);
  cvt_transpose_t<<<dim3(504, 3), 256, 0, stream>>>(W_proj, Wtp, 16128, 96);

  for (int n0 = 0; n0 < NSEQ; n0 += Nc){
    const int    nc  = (NSEQ - n0 < Nc) ? (NSEQ - n0) : Nc;
    const size_t Tc  = (size_t)nc * NS;
    char* cb = wsb + oChunk;
    u16*   h_c   = (u16*)cb;                          // Tc*512 B
    u16*   bufA  = (u16*)(cb + Tc*512);               // Tc*512 B
    u16*   bufB  = (u16*)(cb + Tc*1024);              // Tc*512 B
    u16*   gates = (u16*)(cb + Tc*1536);              // Tc*2048 B
    u16*   gp    = gates;                             // reuse (Tc*768 B)
    float* ptmp  = (float*)(cb + Tc*1536 + Tc*1024);  // overlay in gates tail
    const int t_base = n0*NS;
    const int Tci = (int)Tc;

    patch_embed_ln_v<<<Tci/4, 256, 0, stream>>>(
        x, W_emb, b_emb, ln1_w, ln1_b, h_c, bufA, t_base);

    for (int blk = 0; blk < 2; ++blk){
      if (blk == 1)
        layernorm_v<<<Tci/4, 256, 0, stream>>>(h_c, ln1_w + DDIM, ln1_b + DDIM, bufA);
      conv_silu_v<<<Tci/4, 256, 0, stream>>>(bufA, conv_w + blk*4*DDIM, conv_b + blk*DDIM, bufB);
      mfma_gate2<<<dim3(8, Tci/128), 256, 0, stream>>>(
          bufB, bufA, Wg2 + (size_t)blk*8*8192, gb + blk*4*DDIM, gates);
      slstm_scan5<<<dim3(nc/4, NHEAD), 256, 0, stream>>>(
          gates, Rgt + (size_t)blk*16*4096, bufB);
      gn_res_ln_v<<<Tci/4, 256, 0, stream>>>(
          bufB, gn_w + blk*DDIM, ln2_w + blk*DDIM, ln2_b + blk*DDIM, h_c, bufA);
      mfma_up_gelu4<<<dim3(6, Tci/128), 256, 0, stream>>>(
          bufA, Wu + (size_t)blk*768*256, up_b + blk*2*UPDIM, gp);
      mfma_gemm2<128,128,2,2,4,4,1,4><<<dim3(2, Tci/128), 256, 0, stream>>>(
          gp, UPDIM, Wd + (size_t)blk*256*384, UPDIM,
          dn_b + blk*DDIM, (void*)h_c, DDIM, 12, 0, 0);
    }

    layernorm_v<<<Tci/4, 256, 0, stream>>>(h_c, post_w, post_b, bufA);
    mfma_gemm2<64,96,2,2,2,3,2,0><<<dim3(1, nc/64, KC_PROJ), 256, 0, stream>>>(
        bufA, NS*DDIM, Wtp, NS*DDIM,
        b_proj, (void*)ptmp, PREDN, KCHUNK_PROJ/32, KCHUNK_PROJ, nc);
    proj_out<<<(nc*PREDN + 255)/256, 256, 0, stream>>>(ptmp, b_proj, out, nc, n0);
  }
}

// Round 19
// 637.198 us; speedup vs baseline: 1.1848x; 1.0018x over previous
//
#include <hip/hip_runtime.h>
#include <stdint.h>

typedef unsigned short u16;
typedef unsigned int   u32;
typedef __attribute__((ext_vector_type(8))) short bf16x8;
typedef __attribute__((ext_vector_type(4))) float f32x4;

#define NS      63
#define NSEQ    1024
#define DDIM    256
#define NHEAD   4
#define DHEAD   64
#define UPDIM   384
#define PREDN   96
#define LLEN    512
#define CCH     32
#define PSIZE   16
#define PSTRIDE 8
#define KC_PROJ 28
#define KCHUNK_PROJ 576

__device__ __forceinline__ float bf2f(u32 lo16){
  union { u32 i; float f; } v; v.i = lo16 << 16; return v.f;
}
__device__ __forceinline__ float bf2f_hi(u32 u){
  union { u32 i; float f; } v; v.i = u & 0xffff0000u; return v.f;
}
__device__ __forceinline__ u16 f2bf(float f){
  union { u32 i; float f; } v; v.f = f;
  u32 u = v.i; u += 0x7fffu + ((u >> 16) & 1u);
  return (u16)(u >> 16);
}

__device__ __forceinline__ void gload16(const u16* g, u16* lds){
  __builtin_amdgcn_global_load_lds(
      (const __attribute__((address_space(1))) u32*)g,
      (__attribute__((address_space(3))) u32*)lds, 16, 0, 0);
}

template<int N> __device__ __forceinline__ void waitcnt_vm(){
  if constexpr (N == 0) asm volatile("s_waitcnt vmcnt(0)" ::: "memory");
  else if constexpr (N == 4) asm volatile("s_waitcnt vmcnt(4)" ::: "memory");
  else if constexpr (N == 6) asm volatile("s_waitcnt vmcnt(6)" ::: "memory");
}

// bijective XCD swizzle (m204)
__device__ __forceinline__ void swz_tile(int &nt, int &mt){
  int gx = gridDim.x, gy = gridDim.y;
  int nwg = gx*gy;
  int flat = blockIdx.y*gx + blockIdx.x;
  int c = flat & 7, s = flat >> 3;
  int q = nwg >> 3, r = nwg & 7;
  int base = c*q + (c < r ? c : r);
  int t = base + s;
  nt = t % gx; mt = t / gx;
}

// ---------------- LDS-tiled transpose: dst[c][r] = bf16(src[r][c]) -----------------
__global__ __launch_bounds__(256) void cvt_transpose_t(
    const float* __restrict__ src, u16* __restrict__ dst, int R, int C){
  __shared__ u16 tile[32][33];
  int rb = blockIdx.x*32, cb = blockIdx.y*32;
  int tx = threadIdx.x & 31, ty = threadIdx.x >> 5;
  #pragma unroll
  for (int i = ty; i < 32; i += 8){
    int r = rb + i, c = cb + tx;
    tile[i][tx] = (r < R && c < C) ? f2bf(src[(size_t)r*C + c]) : (u16)0;
  }
  __syncthreads();
  #pragma unroll
  for (int i = ty; i < 32; i += 8){
    int c = cb + i, r = rb + tx;
    if (c < C && r < R) dst[(size_t)c*R + r] = tile[tx][i];
  }
}

__global__ __launch_bounds__(256) void cvt_gate(
    const float* __restrict__ src, u16* __restrict__ dst){
  int mat = blockIdx.x, t = threadIdx.x;
  const float* s = src + (size_t)mat*4096;
  u16* d = dst + (size_t)mat*4096;
  for (int i = t; i < 4096; i += 256){
    int r = i >> 6, c = i & 63;
    d[c*64 + r] = f2bf(s[i]);
  }
}

// gate weight true-K layout, col order n = e*2+gl: dst[(blk*2+p)*4+hd][n][k]
__global__ __launch_bounds__(256) void cvt_gateW2(
    const float* __restrict__ Wg, u16* __restrict__ dst){
  int mi = blockIdx.x;
  int blk = mi >> 3, p = (mi >> 2) & 1, hd = mi & 3;
  u16* d = dst + (size_t)mi*8192;
  for (int i = threadIdx.x; i < 8192; i += 256){
    int n = i >> 6, k = i & 63;
    int e = n >> 1, gl = n & 1;
    int g = 2*p + gl;
    d[i] = f2bf(Wg[((((size_t)blk*4 + g)*4 + hd)*64 + k)*64 + e]);
  }
}

// ---------------- patch embedding + ln1(blk0), wave = token, vectorized ------------
__global__ __launch_bounds__(256) void patch_embed_ln_v(
    const float* __restrict__ x, const float* __restrict__ Wemb,
    const float* __restrict__ bemb, const float* __restrict__ w1,
    const float* __restrict__ b1, u16* __restrict__ h,
    u16* __restrict__ outA, int t_base){
  int wv = blockIdx.x*4 + (threadIdx.x >> 6);
  int lane = threadIdx.x & 63;
  int tg = t_base + wv;
  int n = tg / NS, s = tg - n*NS;
  int b = n >> 5, c = n & 31;
  int l0 = s * PSTRIDE;
  float4 acc = *(const float4*)(bemb + lane*4);
  #pragma unroll
  for (int p = 0; p < PSIZE; ++p){
    float xv = x[((size_t)b*LLEN + l0 + p)*CCH + c];
    float4 we = *(const float4*)(Wemb + p*DDIM + lane*4);
    acc.x += xv*we.x; acc.y += xv*we.y; acc.z += xv*we.z; acc.w += xv*we.w;
  }
  ushort4 hu; hu.x=f2bf(acc.x); hu.y=f2bf(acc.y); hu.z=f2bf(acc.z); hu.w=f2bf(acc.w);
  *(ushort4*)(h + (size_t)wv*DDIM + lane*4) = hu;
  float s1 = acc.x+acc.y+acc.z+acc.w;
  float s2 = acc.x*acc.x+acc.y*acc.y+acc.z*acc.z+acc.w*acc.w;
  #pragma unroll
  for (int o = 1; o < 64; o <<= 1){ s1 += __shfl_xor(s1,o,64); s2 += __shfl_xor(s2,o,64); }
  float mu = s1*(1.f/DDIM);
  float var = s2*(1.f/DDIM) - mu*mu;
  float rstd = rsqrtf(var + 1e-5f);
  float4 wf = *(const float4*)(w1 + lane*4);
  float4 bf = *(const float4*)(b1 + lane*4);
  ushort4 o4;
  o4.x = f2bf((acc.x-mu)*rstd*wf.x + bf.x);
  o4.y = f2bf((acc.y-mu)*rstd*wf.y + bf.y);
  o4.z = f2bf((acc.z-mu)*rstd*wf.z + bf.z);
  o4.w = f2bf((acc.w-mu)*rstd*wf.w + bf.w);
  *(ushort4*)(outA + (size_t)wv*DDIM + lane*4) = o4;
}

// ---------------- layernorm, wave = token, vectorized ------------------------------
__global__ __launch_bounds__(256) void layernorm_v(
    const u16* __restrict__ in, const float* __restrict__ w,
    const float* __restrict__ b, u16* __restrict__ out){
  int wv = blockIdx.x*4 + (threadIdx.x >> 6);
  int lane = threadIdx.x & 63;
  ushort4 u = *(const ushort4*)(in + (size_t)wv*DDIM + lane*4);
  float v0=bf2f(u.x), v1=bf2f(u.y), v2=bf2f(u.z), v3=bf2f(u.w);
  float s1 = v0+v1+v2+v3, s2 = v0*v0+v1*v1+v2*v2+v3*v3;
  #pragma unroll
  for (int o = 1; o < 64; o <<= 1){ s1 += __shfl_xor(s1,o,64); s2 += __shfl_xor(s2,o,64); }
  float mu = s1*(1.f/DDIM);
  float var = s2*(1.f/DDIM) - mu*mu;
  float rstd = rsqrtf(var + 1e-5f);
  float4 wf = *(const float4*)(w + lane*4);
  float4 bf = *(const float4*)(b + lane*4);
  ushort4 o4;
  o4.x = f2bf((v0-mu)*rstd*wf.x + bf.x);
  o4.y = f2bf((v1-mu)*rstd*wf.y + bf.y);
  o4.z = f2bf((v2-mu)*rstd*wf.z + bf.z);
  o4.w = f2bf((v3-mu)*rstd*wf.w + bf.w);
  *(ushort4*)(out + (size_t)wv*DDIM + lane*4) = o4;
}

// ---------------- fused groupnorm + residual + layernorm, vectorized ---------------
__global__ __launch_bounds__(256) void gn_res_ln_v(
    const u16* __restrict__ y, const float* __restrict__ gnw,
    const float* __restrict__ w2, const float* __restrict__ b2,
    u16* __restrict__ h, u16* __restrict__ outA){
  int wv = blockIdx.x*4 + (threadIdx.x >> 6);
  int lane = threadIdx.x & 63;
  ushort4 u = *(const ushort4*)(y + (size_t)wv*DDIM + lane*4);
  float v0=bf2f(u.x), v1=bf2f(u.y), v2=bf2f(u.z), v3=bf2f(u.w);
  float s1 = v0+v1+v2+v3, s2 = v0*v0+v1*v1+v2*v2+v3*v3;
  #pragma unroll
  for (int o = 1; o < 16; o <<= 1){ s1 += __shfl_xor(s1,o,64); s2 += __shfl_xor(s2,o,64); }
  float mu64 = s1*(1.f/64.f);
  float var64 = s2*(1.f/64.f) - mu64*mu64;
  float rstd64 = rsqrtf(var64 + 1e-5f);
  float4 gw = *(const float4*)(gnw + lane*4);
  ushort4 hu = *(const ushort4*)(h + (size_t)wv*DDIM + lane*4);
  float h0 = bf2f(hu.x) + (v0-mu64)*rstd64*gw.x;
  float h1 = bf2f(hu.y) + (v1-mu64)*rstd64*gw.y;
  float h2 = bf2f(hu.z) + (v2-mu64)*rstd64*gw.z;
  float h3 = bf2f(hu.w) + (v3-mu64)*rstd64*gw.w;
  ushort4 hn; hn.x=f2bf(h0); hn.y=f2bf(h1); hn.z=f2bf(h2); hn.w=f2bf(h3);
  *(ushort4*)(h + (size_t)wv*DDIM + lane*4) = hn;
  float t1 = h0+h1+h2+h3, t2 = h0*h0+h1*h1+h2*h2+h3*h3;
  #pragma unroll
  for (int o = 1; o < 64; o <<= 1){ t1 += __shfl_xor(t1,o,64); t2 += __shfl_xor(t2,o,64); }
  float mu = t1*(1.f/DDIM);
  float var = t2*(1.f/DDIM) - mu*mu;
  float rstd = rsqrtf(var + 1e-5f);
  float4 wf = *(const float4*)(w2 + lane*4);
  float4 bf = *(const float4*)(b2 + lane*4);
  ushort4 o4;
  o4.x = f2bf((h0-mu)*rstd*wf.x + bf.x);
  o4.y = f2bf((h1-mu)*rstd*wf.y + bf.y);
  o4.z = f2bf((h2-mu)*rstd*wf.z + bf.z);
  o4.w = f2bf((h3-mu)*rstd*wf.w + bf.w);
  *(ushort4*)(outA + (size_t)wv*DDIM + lane*4) = o4;
}

// ---------------- causal depthwise conv K=4 + SiLU, vectorized ---------------------
__global__ __launch_bounds__(256) void conv_silu_v(
    const u16* __restrict__ xln, const float* __restrict__ cw,
    const float* __restrict__ cb, u16* __restrict__ xc){
  int wv = blockIdx.x*4 + (threadIdx.x >> 6);
  int lane = threadIdx.x & 63;
  int s = wv % NS;
  float4 acc = *(const float4*)(cb + lane*4);
  #pragma unroll
  for (int k = 0; k < 4; ++k){
    int ss = s + k - 3;
    if (ss >= 0){
      ushort4 xu = *(const ushort4*)(xln + (size_t)(wv + k - 3)*DDIM + lane*4);
      float4 cv = *(const float4*)(cw + k*DDIM + lane*4);
      acc.x += bf2f(xu.x)*cv.x; acc.y += bf2f(xu.y)*cv.y;
      acc.z += bf2f(xu.z)*cv.z; acc.w += bf2f(xu.w)*cv.w;
    }
  }
  ushort4 o4;
  o4.x = f2bf(acc.x/(1.f + __expf(-acc.x)));
  o4.y = f2bf(acc.y/(1.f + __expf(-acc.y)));
  o4.z = f2bf(acc.z/(1.f + __expf(-acc.z)));
  o4.w = f2bf(acc.w/(1.f + __expf(-acc.w)));
  *(ushort4*)(xc + (size_t)wv*DDIM + lane*4) = o4;
}

// ---------------- generic MFMA GEMM (XCD-swizzled) ---------------------------------
template<int BM,int BN,int WR,int WC,int MR,int NR,int MODE,int VM>
__global__ __launch_bounds__(256) void mfma_gemm2(
    const u16* __restrict__ A, int lda,
    const u16* __restrict__ Wt, int ldwt,
    const float* __restrict__ bias, void* __restrict__ outp, int ldo,
    int ksteps, int kchunk, int Mtot)
{
  constexpr int nA = BM/16, nW = BN/16;
  __shared__ u16 As[2][BM*32];
  __shared__ u16 Ws[2][BN*32];
  const int tid = threadIdx.x;
  const int lane = tid & 63, wid = tid >> 6;
  const int wr = wid / WC, wc = wid % WC;
  const int fr = lane & 15, kb = lane >> 4;
  int nt, mt; swz_tile(nt, mt);
  const int m0 = mt*BM, n0 = nt*BN;
  const int kc = blockIdx.z;
  const int kbeg = kc*kchunk;
  const u16* Ab = A + (size_t)m0*lda + kbeg;
  const u16* Wb = Wt + (size_t)n0*ldwt + kbeg;
  const int lrow = lane >> 2, lcol = (lane & 3)*8;

  auto stage = [&](int buf, int ks){
    int k0 = ks*32;
    for (int c = wid; c < nA; c += 4)
      gload16(Ab + (size_t)(c*16 + lrow)*lda + k0 + lcol, &As[buf][c*512]);
    for (int c = wid; c < nW; c += 4)
      gload16(Wb + (size_t)(c*16 + lrow)*ldwt + k0 + lcol, &Ws[buf][c*512]);
  };

  f32x4 acc[MR][NR];
  #pragma unroll
  for (int m=0;m<MR;++m)
    #pragma unroll
    for (int n=0;n<NR;++n) acc[m][n] = (f32x4){0.f,0.f,0.f,0.f};

  stage(0, 0);
  if (VM == 0) __syncthreads();
  int cur = 0;
  for (int ks = 0; ks < ksteps; ++ks){
    if (VM == 0){
      if (ks + 1 < ksteps) stage(cur^1, ks+1);
    } else {
      if (ks + 1 < ksteps){ stage(cur^1, ks+1); waitcnt_vm<VM>(); }
      else waitcnt_vm<0>();
      __builtin_amdgcn_s_barrier();
      asm volatile("" ::: "memory");
    }
    bf16x8 af[MR], wf[NR];
    #pragma unroll
    for (int m=0;m<MR;++m)
      af[m] = *(const bf16x8*)&As[cur][(wr*MR*16 + m*16 + fr)*32 + kb*8];
    #pragma unroll
    for (int n=0;n<NR;++n)
      wf[n] = *(const bf16x8*)&Ws[cur][(wc*NR*16 + n*16 + fr)*32 + kb*8];
    #pragma unroll
    for (int m=0;m<MR;++m)
      #pragma unroll
      for (int n=0;n<NR;++n)
        acc[m][n] = __builtin_amdgcn_mfma_f32_16x16x32_bf16(af[m], wf[n], acc[m][n], 0,0,0);
    if (VM == 0){
      __syncthreads();
    } else {
      asm volatile("" ::: "memory");
      __builtin_amdgcn_s_barrier();
    }
    cur ^= 1;
  }
  #pragma unroll
  for (int m=0;m<MR;++m){
    int rowb = m0 + wr*MR*16 + m*16 + kb*4;
    #pragma unroll
    for (int n=0;n<NR;++n){
      int col = n0 + wc*NR*16 + n*16 + fr;
      #pragma unroll
      for (int r=0;r<4;++r){
        int row = rowb + r;
        float v = acc[m][n][r];
        if (MODE == 1){
          u16* dst = (u16*)outp + (size_t)row*ldo + col;
          *dst = f2bf(bf2f(*dst) + v + bias[col]);
        } else {
          ((float*)outp)[((size_t)kc*Mtot + row)*ldo + col] = v;
        }
      }
    }
  }
}

// ---------------- gate GEMM, true K=64 ---------------------------------------------
__global__ __launch_bounds__(256) void mfma_gate2(
    const u16* __restrict__ xc, const u16* __restrict__ xh,
    const u16* __restrict__ Wg2, const float* __restrict__ gb,
    u16* __restrict__ gates)
{
  __shared__ u16 As[2][128*32];
  __shared__ u16 Ws[2][128*32];
  const int tid = threadIdx.x;
  const int lane = tid & 63, wid = tid >> 6;
  const int wr = wid >> 1, wc = wid & 1;
  const int fr = lane & 15, kb = lane >> 4;
  int nt, mt; swz_tile(nt, mt);
  const int p = nt >> 2, hd = nt & 3;
  const int m0 = mt*128;
  const u16* Ain = (p == 0) ? xc : xh;
  const u16* Wb = Wg2 + (size_t)nt*8192;
  const int lrow = lane >> 2, lcol = (lane & 3)*8;

  auto stage = [&](int buf, int ks){
    int k0 = ks*32;
    for (int c = wid; c < 8; c += 4)
      gload16(Ain + (size_t)(m0 + c*16 + lrow)*DDIM + hd*64 + k0 + lcol, &As[buf][c*512]);
    for (int c = wid; c < 8; c += 4)
      gload16(Wb + (size_t)(c*16 + lrow)*64 + k0 + lcol, &Ws[buf][c*512]);
  };

  f32x4 acc[4][4];
  #pragma unroll
  for (int m=0;m<4;++m)
    #pragma unroll
    for (int n=0;n<4;++n) acc[m][n] = (f32x4){0.f,0.f,0.f,0.f};

  stage(0, 0);
  int cur = 0;
  #pragma unroll
  for (int ks = 0; ks < 2; ++ks){
    if (ks == 0){ stage(1, 1); waitcnt_vm<4>(); }
    else waitcnt_vm<0>();
    __builtin_amdgcn_s_barrier();
    asm volatile("" ::: "memory");
    bf16x8 af[4], wf[4];
    #pragma unroll
    for (int m=0;m<4;++m)
      af[m] = *(const bf16x8*)&As[cur][(wr*64 + m*16 + fr)*32 + kb*8];
    #pragma unroll
    for (int n=0;n<4;++n)
      wf[n] = *(const bf16x8*)&Ws[cur][(wc*64 + n*16 + fr)*32 + kb*8];
    #pragma unroll
    for (int m=0;m<4;++m)
      #pragma unroll
      for (int n=0;n<4;++n)
        acc[m][n] = __builtin_amdgcn_mfma_f32_16x16x32_bf16(af[m], wf[n], acc[m][n], 0,0,0);
    asm volatile("" ::: "memory");
    __builtin_amdgcn_s_barrier();
    cur ^= 1;
  }
  #pragma unroll
  for (int m=0;m<4;++m){
    int rowb = m0 + wr*64 + m*16 + kb*4;
    #pragma unroll
    for (int n=0;n<4;++n){
      int cl = wc*64 + n*16 + fr;
      int e = cl >> 1, gl = cl & 1;
      float bv = gb[(2*p + gl)*256 + hd*64 + e];
      int phys = hd*256 + p*128 + cl;
      #pragma unroll
      for (int r=0;r<4;++r)
        gates[(size_t)(rowb + r)*1024 + phys] = f2bf(acc[m][n][r] + bv);
    }
  }
}

// ---------------- FFN up + fast gelu*g2, BM=128 ------------------------------------
__global__ __launch_bounds__(256) void mfma_up_gelu4(
    const u16* __restrict__ A, const u16* __restrict__ Wt,
    const float* __restrict__ ub, u16* __restrict__ gp)
{
  __shared__ u16 As[2][128*32];
  __shared__ u16 Ws[2][128*32];
  const int tid = threadIdx.x;
  const int lane = tid & 63, wid = tid >> 6;
  const int fr = lane & 15, kb = lane >> 4;
  int nt, mt; swz_tile(nt, mt);
  const int m0 = mt*128, n0 = nt*64;
  const u16* W1 = Wt + (size_t)n0*256;
  const u16* W2 = Wt + (size_t)(384 + n0)*256;
  const int lrow = lane >> 2, lcol = (lane & 3)*8;

  auto stage = [&](int buf, int ks){
    int k0 = ks*32;
    for (int c = wid; c < 8; c += 4)
      gload16(A + (size_t)(m0 + c*16 + lrow)*256 + k0 + lcol, &As[buf][c*512]);
    for (int c = wid; c < 8; c += 4){
      const u16* src = (c < 4) ? (W1 + (size_t)(c*16 + lrow)*256)
                               : (W2 + (size_t)((c-4)*16 + lrow)*256);
      gload16(src + k0 + lcol, &Ws[buf][c*512]);
    }
  };

  f32x4 a1[2][4], a2[2][4];
  #pragma unroll
  for (int m=0;m<2;++m)
    #pragma unroll
    for (int n=0;n<4;++n){ a1[m][n]=(f32x4){0,0,0,0}; a2[m][n]=(f32x4){0,0,0,0}; }

  stage(0, 0);
  int cur = 0;
  #pragma unroll
  for (int ks = 0; ks < 8; ++ks){
    if (ks + 1 < 8){ stage(cur^1, ks+1); waitcnt_vm<4>(); }
    else waitcnt_vm<0>();
    __builtin_amdgcn_s_barrier();
    asm volatile("" ::: "memory");
    bf16x8 af[2], wf1[4], wf2[4];
    #pragma unroll
    for (int m=0;m<2;++m)
      af[m] = *(const bf16x8*)&As[cur][(wid*32 + m*16 + fr)*32 + kb*8];
    #pragma unroll
    for (int n=0;n<4;++n){
      wf1[n] = *(const bf16x8*)&Ws[cur][(n*16 + fr)*32 + kb*8];
      wf2[n] = *(const bf16x8*)&Ws[cur][(64 + n*16 + fr)*32 + kb*8];
    }
    #pragma unroll
    for (int m=0;m<2;++m)
      #pragma unroll
      for (int n=0;n<4;++n){
        a1[m][n] = __builtin_amdgcn_mfma_f32_16x16x32_bf16(af[m], wf1[n], a1[m][n], 0,0,0);
        a2[m][n] = __builtin_amdgcn_mfma_f32_16x16x32_bf16(af[m], wf2[n], a2[m][n], 0,0,0);
      }
    asm volatile("" ::: "memory");
    __builtin_amdgcn_s_barrier();
    cur ^= 1;
  }
  #pragma unroll
  for (int m=0;m<2;++m){
    int rowb = m0 + wid*32 + m*16 + kb*4;
    #pragma unroll
    for (int n=0;n<4;++n){
      int col = n0 + n*16 + fr;
      float b1 = ub[col], b2 = ub[384 + col];
      #pragma unroll
      for (int r=0;r<4;++r){
        float g1 = a1[m][n][r] + b1;
        float g2 = a2[m][n][r] + b2;
        float u  = 0.7978845608028654f*(g1 + 0.044715f*g1*g1*g1);
        float uc = fminf(fmaxf(u, -20.f), 20.f);
        float t2 = __expf(uc + uc);
        float th = (t2 - 1.f)/(t2 + 1.f);
        float ge = 0.5f*g1*(1.f + th);
        gp[(size_t)(rowb + r)*UPDIM + col] = f2bf(ge*g2);
      }
    }
  }
}

// ---------------- sLSTM scan v5: 4 seqs/block, 4 blocks/CU -------------------------
__global__ __launch_bounds__(256) void slstm_scan5(
    const u16* __restrict__ gates, const u16* __restrict__ Rgt,
    u16* __restrict__ y)
{
  __shared__ u16 h_lds[16*72];
  __shared__ float rec_lds[4][4][68];
  const int tid = threadIdx.x;
  const int w = tid >> 6, lane = tid & 63;
  const int hd = blockIdx.y, grp = blockIdx.x;
  const int fr = lane & 15, kb = lane >> 4;
  const int seq0 = grp*4;
  const u32* g32 = (const u32*)gates;

  bf16x8 bfr[4][2];
  {
    const u16* rb = Rgt + (size_t)(w*NHEAD + hd)*4096;
    #pragma unroll
    for (int n=0;n<4;++n)
      #pragma unroll
      for (int ks=0;ks<2;++ks)
        bfr[n][ks] = *(const bf16x8*)(rb + (size_t)(n*16 + fr)*64 + ks*32 + kb*8);
  }
  for (int i = tid; i < 16*72/2; i += 256) ((u32*)h_lds)[i] = 0u;
  float c = 0.f, nst = 0.f, m = 0.f;

  const size_t gb = ((size_t)(seq0 + w)*NS)*512 + hd*128 + lane;
  u32 g0[2], g1[2];
  g0[0] = g32[gb];        g0[1] = g32[gb + 64];
  g1[0] = g32[gb + 512];  g1[1] = g32[gb + 576];
  __syncthreads();

  for (int s = 0; s < NS; ++s){
    u32 gn[2] = {0u, 0u};
    if (s + 2 < NS){
      size_t b2 = gb + (size_t)(s+2)*512;
      gn[0] = g32[b2];
      gn[1] = g32[b2 + 64];
    }
    bf16x8 af0 = *(const bf16x8*)&h_lds[fr*72 + kb*8];
    bf16x8 af1 = *(const bf16x8*)&h_lds[fr*72 + 32 + kb*8];
    f32x4 acc[4];
    #pragma unroll
    for (int n=0;n<4;++n){
      acc[n] = (f32x4){0,0,0,0};
      acc[n] = __builtin_amdgcn_mfma_f32_16x16x32_bf16(af0, bfr[n][0], acc[n], 0,0,0);
      acc[n] = __builtin_amdgcn_mfma_f32_16x16x32_bf16(af1, bfr[n][1], acc[n], 0,0,0);
    }
    if (kb == 0){
      #pragma unroll
      for (int n=0;n<4;++n)
        #pragma unroll
        for (int r=0;r<4;++r)
          rec_lds[w][r][n*16 + fr] = acc[n][r];
    }
    asm volatile("s_waitcnt lgkmcnt(0)" ::: "memory");
    __builtin_amdgcn_s_barrier();
    {
      float ip = rec_lds[0][w][lane] + bf2f(g0[0] & 0xffffu);
      float fp = rec_lds[1][w][lane] + bf2f_hi(g0[0]);
      float zp = rec_lds[2][w][lane] + bf2f(g0[1] & 0xffffu);
      float op = rec_lds[3][w][lane] + bf2f_hi(g0[1]);
      float sp  = __logf(1.f + __expf(-fabsf(fp)));
      float lg  = m + fminf(fp, 0.f) - sp;
      float mn  = fmaxf(ip, lg);
      float iv  = __expf(ip - mn);
      float fv  = __expf(lg - mn);
      float zz  = fminf(fabsf(zp), 15.f);
      float t2  = __expf(zz + zz);
      float tha = (t2 - 1.f)/(t2 + 1.f);
      float th  = (zp >= 0.f) ? tha : -tha;
      c   = fv*c + iv*th;
      nst = fv*nst + iv;
      m   = mn;
      float hv = c * __builtin_amdgcn_rcpf(nst*(1.f + __expf(-op)));
      h_lds[w*72 + lane] = f2bf(hv);
      size_t t = (size_t)(seq0 + w)*NS + s;
      y[t*DDIM + hd*64 + lane] = f2bf(hv);
    }
    asm volatile("s_waitcnt lgkmcnt(0)" ::: "memory");
    __builtin_amdgcn_s_barrier();
    g0[0] = g1[0]; g0[1] = g1[1];
    g1[0] = gn[0]; g1[1] = gn[1];
  }
}

// ---------------- proj reduce over K-split slices ----------------------------------
__global__ __launch_bounds__(256) void proj_out(
    const float* __restrict__ ptmp, const float* __restrict__ bproj,
    float* __restrict__ out, int Nc, int n0glob){
  int gid = blockIdx.x*256 + threadIdx.x;
  if (gid >= Nc*PREDN) return;
  float acc = 0.f;
  #pragma unroll
  for (int kc = 0; kc < KC_PROJ; ++kc) acc += ptmp[(size_t)kc*Nc*PREDN + gid];
  int nl = gid / PREDN, j = gid - nl*PREDN;
  int n = n0glob + nl;
  out[((size_t)(n >> 5)*PREDN + j)*CCH + (n & 31)] = acc + bproj[j];
}

extern "C" void kernel_launch(void* const* d_in, const int* in_sizes, int n_in,
                              void* d_out, int out_size, void* d_ws, size_t ws_size,
                              hipStream_t stream) {
  const float* x      = (const float*)d_in[0];
  const float* W_emb  = (const float*)d_in[1];
  const float* b_emb  = (const float*)d_in[2];
  const float* ln1_w  = (const float*)d_in[3];
  const float* ln1_b  = (const float*)d_in[4];
  const float* conv_w = (const float*)d_in[5];
  const float* conv_b = (const float*)d_in[6];
  const float* Wg     = (const float*)d_in[7];
  const float* Rg     = (const float*)d_in[8];
  const float* gb     = (const float*)d_in[9];
  const float* gn_w   = (const float*)d_in[10];
  const float* ln2_w  = (const float*)d_in[11];
  const float* ln2_b  = (const float*)d_in[12];
  const float* up_w   = (const float*)d_in[13];
  const float* up_b   = (const float*)d_in[14];
  const float* dn_w   = (const float*)d_in[15];
  const float* dn_b   = (const float*)d_in[16];
  const float* post_w = (const float*)d_in[17];
  const float* post_b = (const float*)d_in[18];
  const float* W_proj = (const float*)d_in[19];
  const float* b_proj = (const float*)d_in[20];
  float* out = (float*)d_out;

  const size_t oWu   = 0;          // [2][768][256] bf16 : 1,572,864
  const size_t oWd   = 1572864;    // [2][256][384] bf16 :   786,432
  const size_t oWg2  = 2359296;    // [2][8][128][64] bf16 :  262,144
  const size_t oRgt  = 2621440;    // [2][16][64][64] bf16 :  524,288
  const size_t oWp   = 3145728;    // [96][16128] bf16 : 3,096,576
  const size_t oChunk = 6242304;
  const size_t per_seq = (size_t)3584*NS;   // 225,792 B
  int Nc = 0;
  const int cands[3] = {1024, 512, 256};
  for (int i = 0; i < 3; ++i)
    if (oChunk + (size_t)cands[i]*per_seq <= ws_size){ Nc = cands[i]; break; }
  if (Nc == 0) return;

  char* wsb = (char*)d_ws;
  u16* Wu   = (u16*)(wsb + oWu);
  u16* Wd   = (u16*)(wsb + oWd);
  u16* Wg2  = (u16*)(wsb + oWg2);
  u16* Rgt  = (u16*)(wsb + oRgt);
  u16* Wtp  = (u16*)(wsb + oWp);

  for (int blk = 0; blk < 2; ++blk){
    cvt_transpose_t<<<dim3(8, 24), 256, 0, stream>>>(
        up_w + (size_t)blk*256*768, Wu + (size_t)blk*768*256, 256, 768);
    cvt_transpose_t<<<dim3(12, 8), 256, 0, stream>>>(
        dn_w + (size_t)blk*384*256, Wd + (size_t)blk*256*384, 384, 256);
  }
  cvt_gateW2<<<16, 256, 0, stream>>>(Wg, Wg2);
  cvt_gate<<<32, 256, 0, stream>>>(Rg, Rgt);
  cvt_transpose_t<<<dim3(504, 3), 256, 0, stream>>>(W_proj, Wtp, 16128, 96);

  for (int n0 = 0; n0 < NSEQ; n0 += Nc){
    const int    nc  = (NSEQ - n0 < Nc) ? (NSEQ - n0) : Nc;
    const size_t Tc  = (size_t)nc * NS;
    char* cb = wsb + oChunk;
    u16*   h_c   = (u16*)cb;                          // Tc*512 B
    u16*   bufA  = (u16*)(cb + Tc*512);               // Tc*512 B
    u16*   bufB  = (u16*)(cb + Tc*1024);              // Tc*512 B
    u16*   gates = (u16*)(cb + Tc*1536);              // Tc*2048 B
    u16*   gp    = gates;                             // reuse (Tc*768 B)
    float* ptmp  = (float*)(cb + Tc*1536 + Tc*1024);  // overlay in gates tail
    const int t_base = n0*NS;
    const int Tci = (int)Tc;

    patch_embed_ln_v<<<Tci/4, 256, 0, stream>>>(
        x, W_emb, b_emb, ln1_w, ln1_b, h_c, bufA, t_base);

    for (int blk = 0; blk < 2; ++blk){
      if (blk == 1)
        layernorm_v<<<Tci/4, 256, 0, stream>>>(h_c, ln1_w + DDIM, ln1_b + DDIM, bufA);
      conv_silu_v<<<Tci/4, 256, 0, stream>>>(bufA, conv_w + blk*4*DDIM, conv_b + blk*DDIM, bufB);
      mfma_gate2<<<dim3(8, Tci/128), 256, 0, stream>>>(
          bufB, bufA, Wg2 + (size_t)blk*8*8192, gb + blk*4*DDIM, gates);
      slstm_scan5<<<dim3(nc/4, NHEAD), 256, 0, stream>>>(
          gates, Rgt + (size_t)blk*16*4096, bufB);
      gn_res_ln_v<<<Tci/4, 256, 0, stream>>>(
          bufB, gn_w + blk*DDIM, ln2_w + blk*DDIM, ln2_b + blk*DDIM, h_c, bufA);
      mfma_up_gelu4<<<dim3(6, Tci/128), 256, 0, stream>>>(
          bufA, Wu + (size_t)blk*768*256, up_b + blk*2*UPDIM, gp);
      mfma_gemm2<128,128,2,2,4,4,1,4><<<dim3(2, Tci/128), 256, 0, stream>>>(
          gp, UPDIM, Wd + (size_t)blk*256*384, UPDIM,
          dn_b + blk*DDIM, (void*)h_c, DDIM, 12, 0, 0);
    }

    layernorm_v<<<Tci/4, 256, 0, stream>>>(h_c, post_w, post_b, bufA);
    mfma_gemm2<64,96,2,2,2,3,2,0><<<dim3(1, nc/64, KC_PROJ), 256, 0, stream>>>(
        bufA, NS*DDIM, Wtp, NS*DDIM,
        b_proj, (void*)ptmp, PREDN, KCHUNK_PROJ/32, KCHUNK_PROJ, nc);
    proj_out<<<(nc*PREDN + 255)/256, 256, 0, stream>>>(ptmp, b_proj, out, nc, n0);
  }
}

// Round 20
// 635.316 us; speedup vs baseline: 1.1883x; 1.0030x over previous
//
#include <hip/hip_runtime.h>
#include <stdint.h>

typedef unsigned short u16;
typedef unsigned int   u32;
typedef __attribute__((ext_vector_type(8))) short bf16x8;
typedef __attribute__((ext_vector_type(4))) float f32x4;

#define NS      63
#define NSEQ    1024
#define DDIM    256
#define NHEAD   4
#define DHEAD   64
#define UPDIM   384
#define PREDN   96
#define LLEN    512
#define CCH     32
#define PSIZE   16
#define PSTRIDE 8
#define KC_PROJ 28
#define KCHUNK_PROJ 576

__device__ __forceinline__ float bf2f(u32 lo16){
  union { u32 i; float f; } v; v.i = lo16 << 16; return v.f;
}
__device__ __forceinline__ float bf2f_hi(u32 u){
  union { u32 i; float f; } v; v.i = u & 0xffff0000u; return v.f;
}
__device__ __forceinline__ u16 f2bf(float f){
  union { u32 i; float f; } v; v.f = f;
  u32 u = v.i; u += 0x7fffu + ((u >> 16) & 1u);
  return (u16)(u >> 16);
}

__device__ __forceinline__ void gload16(const u16* g, u16* lds){
  __builtin_amdgcn_global_load_lds(
      (const __attribute__((address_space(1))) u32*)g,
      (__attribute__((address_space(3))) u32*)lds, 16, 0, 0);
}

template<int N> __device__ __forceinline__ void waitcnt_vm(){
  if constexpr (N == 0) asm volatile("s_waitcnt vmcnt(0)" ::: "memory");
  else if constexpr (N == 4) asm volatile("s_waitcnt vmcnt(4)" ::: "memory");
  else if constexpr (N == 6) asm volatile("s_waitcnt vmcnt(6)" ::: "memory");
}

// bijective XCD swizzle (m204)
__device__ __forceinline__ void swz_tile(int &nt, int &mt){
  int gx = gridDim.x, gy = gridDim.y;
  int nwg = gx*gy;
  int flat = blockIdx.y*gx + blockIdx.x;
  int c = flat & 7, s = flat >> 3;
  int q = nwg >> 3, r = nwg & 7;
  int base = c*q + (c < r ? c : r);
  int t = base + s;
  nt = t % gx; mt = t / gx;
}

// ---------------- LDS-tiled transpose: dst[c][r] = bf16(src[r][c]) -----------------
__global__ __launch_bounds__(256) void cvt_transpose_t(
    const float* __restrict__ src, u16* __restrict__ dst, int R, int C){
  __shared__ u16 tile[32][33];
  int rb = blockIdx.x*32, cb = blockIdx.y*32;
  int tx = threadIdx.x & 31, ty = threadIdx.x >> 5;
  #pragma unroll
  for (int i = ty; i < 32; i += 8){
    int r = rb + i, c = cb + tx;
    tile[i][tx] = (r < R && c < C) ? f2bf(src[(size_t)r*C + c]) : (u16)0;
  }
  __syncthreads();
  #pragma unroll
  for (int i = ty; i < 32; i += 8){
    int c = cb + i, r = rb + tx;
    if (c < C && r < R) dst[(size_t)c*R + r] = tile[tx][i];
  }
}

__global__ __launch_bounds__(256) void cvt_gate(
    const float* __restrict__ src, u16* __restrict__ dst){
  int mat = blockIdx.x, t = threadIdx.x;
  const float* s = src + (size_t)mat*4096;
  u16* d = dst + (size_t)mat*4096;
  for (int i = t; i < 4096; i += 256){
    int r = i >> 6, c = i & 63;
    d[c*64 + r] = f2bf(s[i]);
  }
}

// gate weight true-K layout, col order n = e*2+gl: dst[(blk*2+p)*4+hd][n][k]
__global__ __launch_bounds__(256) void cvt_gateW2(
    const float* __restrict__ Wg, u16* __restrict__ dst){
  int mi = blockIdx.x;
  int blk = mi >> 3, p = (mi >> 2) & 1, hd = mi & 3;
  u16* d = dst + (size_t)mi*8192;
  for (int i = threadIdx.x; i < 8192; i += 256){
    int n = i >> 6, k = i & 63;
    int e = n >> 1, gl = n & 1;
    int g = 2*p + gl;
    d[i] = f2bf(Wg[((((size_t)blk*4 + g)*4 + hd)*64 + k)*64 + e]);
  }
}

// ---------------- patch embedding + ln1(blk0), wave = token, vectorized ------------
__global__ __launch_bounds__(256) void patch_embed_ln_v(
    const float* __restrict__ x, const float* __restrict__ Wemb,
    const float* __restrict__ bemb, const float* __restrict__ w1,
    const float* __restrict__ b1, u16* __restrict__ h,
    u16* __restrict__ outA, int t_base){
  int wv = blockIdx.x*4 + (threadIdx.x >> 6);
  int lane = threadIdx.x & 63;
  int tg = t_base + wv;
  int n = tg / NS, s = tg - n*NS;
  int b = n >> 5, c = n & 31;
  int l0 = s * PSTRIDE;
  float4 acc = *(const float4*)(bemb + lane*4);
  #pragma unroll
  for (int p = 0; p < PSIZE; ++p){
    float xv = x[((size_t)b*LLEN + l0 + p)*CCH + c];
    float4 we = *(const float4*)(Wemb + p*DDIM + lane*4);
    acc.x += xv*we.x; acc.y += xv*we.y; acc.z += xv*we.z; acc.w += xv*we.w;
  }
  ushort4 hu; hu.x=f2bf(acc.x); hu.y=f2bf(acc.y); hu.z=f2bf(acc.z); hu.w=f2bf(acc.w);
  *(ushort4*)(h + (size_t)wv*DDIM + lane*4) = hu;
  float s1 = acc.x+acc.y+acc.z+acc.w;
  float s2 = acc.x*acc.x+acc.y*acc.y+acc.z*acc.z+acc.w*acc.w;
  #pragma unroll
  for (int o = 1; o < 64; o <<= 1){ s1 += __shfl_xor(s1,o,64); s2 += __shfl_xor(s2,o,64); }
  float mu = s1*(1.f/DDIM);
  float var = s2*(1.f/DDIM) - mu*mu;
  float rstd = rsqrtf(var + 1e-5f);
  float4 wf = *(const float4*)(w1 + lane*4);
  float4 bf = *(const float4*)(b1 + lane*4);
  ushort4 o4;
  o4.x = f2bf((acc.x-mu)*rstd*wf.x + bf.x);
  o4.y = f2bf((acc.y-mu)*rstd*wf.y + bf.y);
  o4.z = f2bf((acc.z-mu)*rstd*wf.z + bf.z);
  o4.w = f2bf((acc.w-mu)*rstd*wf.w + bf.w);
  *(ushort4*)(outA + (size_t)wv*DDIM + lane*4) = o4;
}

// ---------------- layernorm, wave = token, vectorized ------------------------------
__global__ __launch_bounds__(256) void layernorm_v(
    const u16* __restrict__ in, const float* __restrict__ w,
    const float* __restrict__ b, u16* __restrict__ out){
  int wv = blockIdx.x*4 + (threadIdx.x >> 6);
  int lane = threadIdx.x & 63;
  ushort4 u = *(const ushort4*)(in + (size_t)wv*DDIM + lane*4);
  float v0=bf2f(u.x), v1=bf2f(u.y), v2=bf2f(u.z), v3=bf2f(u.w);
  float s1 = v0+v1+v2+v3, s2 = v0*v0+v1*v1+v2*v2+v3*v3;
  #pragma unroll
  for (int o = 1; o < 64; o <<= 1){ s1 += __shfl_xor(s1,o,64); s2 += __shfl_xor(s2,o,64); }
  float mu = s1*(1.f/DDIM);
  float var = s2*(1.f/DDIM) - mu*mu;
  float rstd = rsqrtf(var + 1e-5f);
  float4 wf = *(const float4*)(w + lane*4);
  float4 bf = *(const float4*)(b + lane*4);
  ushort4 o4;
  o4.x = f2bf((v0-mu)*rstd*wf.x + bf.x);
  o4.y = f2bf((v1-mu)*rstd*wf.y + bf.y);
  o4.z = f2bf((v2-mu)*rstd*wf.z + bf.z);
  o4.w = f2bf((v3-mu)*rstd*wf.w + bf.w);
  *(ushort4*)(out + (size_t)wv*DDIM + lane*4) = o4;
}

// ---------------- fused groupnorm + residual + layernorm, vectorized ---------------
__global__ __launch_bounds__(256) void gn_res_ln_v(
    const u16* __restrict__ y, const float* __restrict__ gnw,
    const float* __restrict__ w2, const float* __restrict__ b2,
    u16* __restrict__ h, u16* __restrict__ outA){
  int wv = blockIdx.x*4 + (threadIdx.x >> 6);
  int lane = threadIdx.x & 63;
  ushort4 u = *(const ushort4*)(y + (size_t)wv*DDIM + lane*4);
  float v0=bf2f(u.x), v1=bf2f(u.y), v2=bf2f(u.z), v3=bf2f(u.w);
  float s1 = v0+v1+v2+v3, s2 = v0*v0+v1*v1+v2*v2+v3*v3;
  #pragma unroll
  for (int o = 1; o < 16; o <<= 1){ s1 += __shfl_xor(s1,o,64); s2 += __shfl_xor(s2,o,64); }
  float mu64 = s1*(1.f/64.f);
  float var64 = s2*(1.f/64.f) - mu64*mu64;
  float rstd64 = rsqrtf(var64 + 1e-5f);
  float4 gw = *(const float4*)(gnw + lane*4);
  ushort4 hu = *(const ushort4*)(h + (size_t)wv*DDIM + lane*4);
  float h0 = bf2f(hu.x) + (v0-mu64)*rstd64*gw.x;
  float h1 = bf2f(hu.y) + (v1-mu64)*rstd64*gw.y;
  float h2 = bf2f(hu.z) + (v2-mu64)*rstd64*gw.z;
  float h3 = bf2f(hu.w) + (v3-mu64)*rstd64*gw.w;
  ushort4 hn; hn.x=f2bf(h0); hn.y=f2bf(h1); hn.z=f2bf(h2); hn.w=f2bf(h3);
  *(ushort4*)(h + (size_t)wv*DDIM + lane*4) = hn;
  float t1 = h0+h1+h2+h3, t2 = h0*h0+h1*h1+h2*h2+h3*h3;
  #pragma unroll
  for (int o = 1; o < 64; o <<= 1){ t1 += __shfl_xor(t1,o,64); t2 += __shfl_xor(t2,o,64); }
  float mu = t1*(1.f/DDIM);
  float var = t2*(1.f/DDIM) - mu*mu;
  float rstd = rsqrtf(var + 1e-5f);
  float4 wf = *(const float4*)(w2 + lane*4);
  float4 bf = *(const float4*)(b2 + lane*4);
  ushort4 o4;
  o4.x = f2bf((h0-mu)*rstd*wf.x + bf.x);
  o4.y = f2bf((h1-mu)*rstd*wf.y + bf.y);
  o4.z = f2bf((h2-mu)*rstd*wf.z + bf.z);
  o4.w = f2bf((h3-mu)*rstd*wf.w + bf.w);
  *(ushort4*)(outA + (size_t)wv*DDIM + lane*4) = o4;
}

// ---------------- causal depthwise conv K=4 + SiLU, vectorized ---------------------
__global__ __launch_bounds__(256) void conv_silu_v(
    const u16* __restrict__ xln, const float* __restrict__ cw,
    const float* __restrict__ cb, u16* __restrict__ xc){
  int wv = blockIdx.x*4 + (threadIdx.x >> 6);
  int lane = threadIdx.x & 63;
  int s = wv % NS;
  float4 acc = *(const float4*)(cb + lane*4);
  #pragma unroll
  for (int k = 0; k < 4; ++k){
    int ss = s + k - 3;
    if (ss >= 0){
      ushort4 xu = *(const ushort4*)(xln + (size_t)(wv + k - 3)*DDIM + lane*4);
      float4 cv = *(const float4*)(cw + k*DDIM + lane*4);
      acc.x += bf2f(xu.x)*cv.x; acc.y += bf2f(xu.y)*cv.y;
      acc.z += bf2f(xu.z)*cv.z; acc.w += bf2f(xu.w)*cv.w;
    }
  }
  ushort4 o4;
  o4.x = f2bf(acc.x/(1.f + __expf(-acc.x)));
  o4.y = f2bf(acc.y/(1.f + __expf(-acc.y)));
  o4.z = f2bf(acc.z/(1.f + __expf(-acc.z)));
  o4.w = f2bf(acc.w/(1.f + __expf(-acc.w)));
  *(ushort4*)(xc + (size_t)wv*DDIM + lane*4) = o4;
}

// ---------------- generic MFMA GEMM (XCD-swizzled) ---------------------------------
template<int BM,int BN,int WR,int WC,int MR,int NR,int MODE,int VM>
__global__ __launch_bounds__(256) void mfma_gemm2(
    const u16* __restrict__ A, int lda,
    const u16* __restrict__ Wt, int ldwt,
    const float* __restrict__ bias, void* __restrict__ outp, int ldo,
    int ksteps, int kchunk, int Mtot)
{
  constexpr int nA = BM/16, nW = BN/16;
  __shared__ u16 As[2][BM*32];
  __shared__ u16 Ws[2][BN*32];
  const int tid = threadIdx.x;
  const int lane = tid & 63, wid = tid >> 6;
  const int wr = wid / WC, wc = wid % WC;
  const int fr = lane & 15, kb = lane >> 4;
  int nt, mt; swz_tile(nt, mt);
  const int m0 = mt*BM, n0 = nt*BN;
  const int kc = blockIdx.z;
  const int kbeg = kc*kchunk;
  const u16* Ab = A + (size_t)m0*lda + kbeg;
  const u16* Wb = Wt + (size_t)n0*ldwt + kbeg;
  const int lrow = lane >> 2, lcol = (lane & 3)*8;

  auto stage = [&](int buf, int ks){
    int k0 = ks*32;
    for (int c = wid; c < nA; c += 4)
      gload16(Ab + (size_t)(c*16 + lrow)*lda + k0 + lcol, &As[buf][c*512]);
    for (int c = wid; c < nW; c += 4)
      gload16(Wb + (size_t)(c*16 + lrow)*ldwt + k0 + lcol, &Ws[buf][c*512]);
  };

  f32x4 acc[MR][NR];
  #pragma unroll
  for (int m=0;m<MR;++m)
    #pragma unroll
    for (int n=0;n<NR;++n) acc[m][n] = (f32x4){0.f,0.f,0.f,0.f};

  stage(0, 0);
  if (VM == 0) __syncthreads();
  int cur = 0;
  for (int ks = 0; ks < ksteps; ++ks){
    if (VM == 0){
      if (ks + 1 < ksteps) stage(cur^1, ks+1);
    } else {
      if (ks + 1 < ksteps){ stage(cur^1, ks+1); waitcnt_vm<VM>(); }
      else waitcnt_vm<0>();
      __builtin_amdgcn_s_barrier();
      asm volatile("" ::: "memory");
    }
    bf16x8 af[MR], wf[NR];
    #pragma unroll
    for (int m=0;m<MR;++m)
      af[m] = *(const bf16x8*)&As[cur][(wr*MR*16 + m*16 + fr)*32 + kb*8];
    #pragma unroll
    for (int n=0;n<NR;++n)
      wf[n] = *(const bf16x8*)&Ws[cur][(wc*NR*16 + n*16 + fr)*32 + kb*8];
    #pragma unroll
    for (int m=0;m<MR;++m)
      #pragma unroll
      for (int n=0;n<NR;++n)
        acc[m][n] = __builtin_amdgcn_mfma_f32_16x16x32_bf16(af[m], wf[n], acc[m][n], 0,0,0);
    if (VM == 0){
      __syncthreads();
    } else {
      asm volatile("" ::: "memory");
      __builtin_amdgcn_s_barrier();
    }
    cur ^= 1;
  }
  #pragma unroll
  for (int m=0;m<MR;++m){
    int rowb = m0 + wr*MR*16 + m*16 + kb*4;
    #pragma unroll
    for (int n=0;n<NR;++n){
      int col = n0 + wc*NR*16 + n*16 + fr;
      #pragma unroll
      for (int r=0;r<4;++r){
        int row = rowb + r;
        float v = acc[m][n][r];
        if (MODE == 1){
          u16* dst = (u16*)outp + (size_t)row*ldo + col;
          *dst = f2bf(bf2f(*dst) + v + bias[col]);
        } else {
          ((float*)outp)[((size_t)kc*Mtot + row)*ldo + col] = v;
        }
      }
    }
  }
}

// ---------------- gate GEMM, true K=64 ---------------------------------------------
__global__ __launch_bounds__(256) void mfma_gate2(
    const u16* __restrict__ xc, const u16* __restrict__ xh,
    const u16* __restrict__ Wg2, const float* __restrict__ gb,
    u16* __restrict__ gates)
{
  __shared__ u16 As[2][128*32];
  __shared__ u16 Ws[2][128*32];
  const int tid = threadIdx.x;
  const int lane = tid & 63, wid = tid >> 6;
  const int wr = wid >> 1, wc = wid & 1;
  const int fr = lane & 15, kb = lane >> 4;
  int nt, mt; swz_tile(nt, mt);
  const int p = nt >> 2, hd = nt & 3;
  const int m0 = mt*128;
  const u16* Ain = (p == 0) ? xc : xh;
  const u16* Wb = Wg2 + (size_t)nt*8192;
  const int lrow = lane >> 2, lcol = (lane & 3)*8;

  auto stage = [&](int buf, int ks){
    int k0 = ks*32;
    for (int c = wid; c < 8; c += 4)
      gload16(Ain + (size_t)(m0 + c*16 + lrow)*DDIM + hd*64 + k0 + lcol, &As[buf][c*512]);
    for (int c = wid; c < 8; c += 4)
      gload16(Wb + (size_t)(c*16 + lrow)*64 + k0 + lcol, &Ws[buf][c*512]);
  };

  f32x4 acc[4][4];
  #pragma unroll
  for (int m=0;m<4;++m)
    #pragma unroll
    for (int n=0;n<4;++n) acc[m][n] = (f32x4){0.f,0.f,0.f,0.f};

  stage(0, 0);
  int cur = 0;
  #pragma unroll
  for (int ks = 0; ks < 2; ++ks){
    if (ks == 0){ stage(1, 1); waitcnt_vm<4>(); }
    else waitcnt_vm<0>();
    __builtin_amdgcn_s_barrier();
    asm volatile("" ::: "memory");
    bf16x8 af[4], wf[4];
    #pragma unroll
    for (int m=0;m<4;++m)
      af[m] = *(const bf16x8*)&As[cur][(wr*64 + m*16 + fr)*32 + kb*8];
    #pragma unroll
    for (int n=0;n<4;++n)
      wf[n] = *(const bf16x8*)&Ws[cur][(wc*64 + n*16 + fr)*32 + kb*8];
    #pragma unroll
    for (int m=0;m<4;++m)
      #pragma unroll
      for (int n=0;n<4;++n)
        acc[m][n] = __builtin_amdgcn_mfma_f32_16x16x32_bf16(af[m], wf[n], acc[m][n], 0,0,0);
    asm volatile("" ::: "memory");
    __builtin_amdgcn_s_barrier();
    cur ^= 1;
  }
  #pragma unroll
  for (int m=0;m<4;++m){
    int rowb = m0 + wr*64 + m*16 + kb*4;
    #pragma unroll
    for (int n=0;n<4;++n){
      int cl = wc*64 + n*16 + fr;
      int e = cl >> 1, gl = cl & 1;
      float bv = gb[(2*p + gl)*256 + hd*64 + e];
      int phys = hd*256 + p*128 + cl;
      #pragma unroll
      for (int r=0;r<4;++r)
        gates[(size_t)(rowb + r)*1024 + phys] = f2bf(acc[m][n][r] + bv);
    }
  }
}

// ---------------- FFN up + fast gelu*g2, BM=128 ------------------------------------
__global__ __launch_bounds__(256) void mfma_up_gelu4(
    const u16* __restrict__ A, const u16* __restrict__ Wt,
    const float* __restrict__ ub, u16* __restrict__ gp)
{
  __shared__ u16 As[2][128*32];
  __shared__ u16 Ws[2][128*32];
  const int tid = threadIdx.x;
  const int lane = tid & 63, wid = tid >> 6;
  const int fr = lane & 15, kb = lane >> 4;
  int nt, mt; swz_tile(nt, mt);
  const int m0 = mt*128, n0 = nt*64;
  const u16* W1 = Wt + (size_t)n0*256;
  const u16* W2 = Wt + (size_t)(384 + n0)*256;
  const int lrow = lane >> 2, lcol = (lane & 3)*8;

  auto stage = [&](int buf, int ks){
    int k0 = ks*32;
    for (int c = wid; c < 8; c += 4)
      gload16(A + (size_t)(m0 + c*16 + lrow)*256 + k0 + lcol, &As[buf][c*512]);
    for (int c = wid; c < 8; c += 4){
      const u16* src = (c < 4) ? (W1 + (size_t)(c*16 + lrow)*256)
                               : (W2 + (size_t)((c-4)*16 + lrow)*256);
      gload16(src + k0 + lcol, &Ws[buf][c*512]);
    }
  };

  f32x4 a1[2][4], a2[2][4];
  #pragma unroll
  for (int m=0;m<2;++m)
    #pragma unroll
    for (int n=0;n<4;++n){ a1[m][n]=(f32x4){0,0,0,0}; a2[m][n]=(f32x4){0,0,0,0}; }

  stage(0, 0);
  int cur = 0;
  #pragma unroll
  for (int ks = 0; ks < 8; ++ks){
    if (ks + 1 < 8){ stage(cur^1, ks+1); waitcnt_vm<4>(); }
    else waitcnt_vm<0>();
    __builtin_amdgcn_s_barrier();
    asm volatile("" ::: "memory");
    bf16x8 af[2], wf1[4], wf2[4];
    #pragma unroll
    for (int m=0;m<2;++m)
      af[m] = *(const bf16x8*)&As[cur][(wid*32 + m*16 + fr)*32 + kb*8];
    #pragma unroll
    for (int n=0;n<4;++n){
      wf1[n] = *(const bf16x8*)&Ws[cur][(n*16 + fr)*32 + kb*8];
      wf2[n] = *(const bf16x8*)&Ws[cur][(64 + n*16 + fr)*32 + kb*8];
    }
    #pragma unroll
    for (int m=0;m<2;++m)
      #pragma unroll
      for (int n=0;n<4;++n){
        a1[m][n] = __builtin_amdgcn_mfma_f32_16x16x32_bf16(af[m], wf1[n], a1[m][n], 0,0,0);
        a2[m][n] = __builtin_amdgcn_mfma_f32_16x16x32_bf16(af[m], wf2[n], a2[m][n], 0,0,0);
      }
    asm volatile("" ::: "memory");
    __builtin_amdgcn_s_barrier();
    cur ^= 1;
  }
  #pragma unroll
  for (int m=0;m<2;++m){
    int rowb = m0 + wid*32 + m*16 + kb*4;
    #pragma unroll
    for (int n=0;n<4;++n){
      int col = n0 + n*16 + fr;
      float b1 = ub[col], b2 = ub[384 + col];
      #pragma unroll
      for (int r=0;r<4;++r){
        float g1 = a1[m][n][r] + b1;
        float g2 = a2[m][n][r] + b2;
        float u  = 0.7978845608028654f*(g1 + 0.044715f*g1*g1*g1);
        float uc = fminf(fmaxf(u, -20.f), 20.f);
        float t2 = __expf(uc + uc);
        float th = (t2 - 1.f)/(t2 + 1.f);
        float ge = 0.5f*g1*(1.f + th);
        gp[(size_t)(rowb + r)*UPDIM + col] = f2bf(ge*g2);
      }
    }
  }
}

// ---------------- sLSTM scan v5b: 4 seqs/block + single-exp algebra + setprio ------
__global__ __launch_bounds__(256) void slstm_scan5(
    const u16* __restrict__ gates, const u16* __restrict__ Rgt,
    u16* __restrict__ y)
{
  __shared__ u16 h_lds[16*72];
  __shared__ float rec_lds[4][4][68];
  const int tid = threadIdx.x;
  const int w = tid >> 6, lane = tid & 63;
  const int hd = blockIdx.y, grp = blockIdx.x;
  const int fr = lane & 15, kb = lane >> 4;
  const int seq0 = grp*4;
  const u32* g32 = (const u32*)gates;

  bf16x8 bfr[4][2];
  {
    const u16* rb = Rgt + (size_t)(w*NHEAD + hd)*4096;
    #pragma unroll
    for (int n=0;n<4;++n)
      #pragma unroll
      for (int ks=0;ks<2;++ks)
        bfr[n][ks] = *(const bf16x8*)(rb + (size_t)(n*16 + fr)*64 + ks*32 + kb*8);
  }
  for (int i = tid; i < 16*72/2; i += 256) ((u32*)h_lds)[i] = 0u;
  float c = 0.f, nst = 0.f, m = 0.f;

  const size_t gb = ((size_t)(seq0 + w)*NS)*512 + hd*128 + lane;
  u32 g0[2], g1[2];
  g0[0] = g32[gb];        g0[1] = g32[gb + 64];
  g1[0] = g32[gb + 512];  g1[1] = g32[gb + 576];
  __syncthreads();

  for (int s = 0; s < NS; ++s){
    u32 gn[2] = {0u, 0u};
    if (s + 2 < NS){
      size_t b2 = gb + (size_t)(s+2)*512;
      gn[0] = g32[b2];
      gn[1] = g32[b2 + 64];
    }
    bf16x8 af0 = *(const bf16x8*)&h_lds[fr*72 + kb*8];
    bf16x8 af1 = *(const bf16x8*)&h_lds[fr*72 + 32 + kb*8];
    f32x4 acc[4];
    __builtin_amdgcn_s_setprio(1);
    #pragma unroll
    for (int n=0;n<4;++n){
      acc[n] = (f32x4){0,0,0,0};
      acc[n] = __builtin_amdgcn_mfma_f32_16x16x32_bf16(af0, bfr[n][0], acc[n], 0,0,0);
      acc[n] = __builtin_amdgcn_mfma_f32_16x16x32_bf16(af1, bfr[n][1], acc[n], 0,0,0);
    }
    __builtin_amdgcn_s_setprio(0);
    if (kb == 0){
      #pragma unroll
      for (int n=0;n<4;++n)
        #pragma unroll
        for (int r=0;r<4;++r)
          rec_lds[w][r][n*16 + fr] = acc[n][r];
    }
    asm volatile("s_waitcnt lgkmcnt(0)" ::: "memory");
    __builtin_amdgcn_s_barrier();
    {
      float ip = rec_lds[0][w][lane] + bf2f(g0[0] & 0xffffu);
      float fp = rec_lds[1][w][lane] + bf2f_hi(g0[0]);
      float zp = rec_lds[2][w][lane] + bf2f(g0[1] & 0xffffu);
      float op = rec_lds[3][w][lane] + bf2f_hi(g0[1]);
      float sp  = __logf(1.f + __expf(-fabsf(fp)));
      float lg  = m + fminf(fp, 0.f) - sp;
      float dd  = ip - lg;
      float ed  = __expf(-fabsf(dd));
      float iv  = (dd >= 0.f) ? 1.f : ed;
      float fv  = (dd >= 0.f) ? ed : 1.f;
      m = fmaxf(ip, lg);
      float zz  = fminf(fabsf(zp), 15.f);
      float t2  = __expf(zz + zz);
      float tha = (t2 - 1.f)/(t2 + 1.f);
      float th  = (zp >= 0.f) ? tha : -tha;
      c   = fv*c + iv*th;
      nst = fv*nst + iv;
      float hv = c * __builtin_amdgcn_rcpf(nst*(1.f + __expf(-op)));
      h_lds[w*72 + lane] = f2bf(hv);
      size_t t = (size_t)(seq0 + w)*NS + s;
      y[t*DDIM + hd*64 + lane] = f2bf(hv);
    }
    asm volatile("s_waitcnt lgkmcnt(0)" ::: "memory");
    __builtin_amdgcn_s_barrier();
    g0[0] = g1[0]; g0[1] = g1[1];
    g1[0] = gn[0]; g1[1] = gn[1];
  }
}

// ---------------- proj reduce over K-split slices ----------------------------------
__global__ __launch_bounds__(256) void proj_out(
    const float* __restrict__ ptmp, const float* __restrict__ bproj,
    float* __restrict__ out, int Nc, int n0glob){
  int gid = blockIdx.x*256 + threadIdx.x;
  if (gid >= Nc*PREDN) return;
  float acc = 0.f;
  #pragma unroll
  for (int kc = 0; kc < KC_PROJ; ++kc) acc += ptmp[(size_t)kc*Nc*PREDN + gid];
  int nl = gid / PREDN, j = gid - nl*PREDN;
  int n = n0glob + nl;
  out[((size_t)(n >> 5)*PREDN + j)*CCH + (n & 31)] = acc + bproj[j];
}

extern "C" void kernel_launch(void* const* d_in, const int* in_sizes, int n_in,
                              void* d_out, int out_size, void* d_ws, size_t ws_size,
                              hipStream_t stream) {
  const float* x      = (const float*)d_in[0];
  const float* W_emb  = (const float*)d_in[1];
  const float* b_emb  = (const float*)d_in[2];
  const float* ln1_w  = (const float*)d_in[3];
  const float* ln1_b  = (const float*)d_in[4];
  const float* conv_w = (const float*)d_in[5];
  const float* conv_b = (const float*)d_in[6];
  const float* Wg     = (const float*)d_in[7];
  const float* Rg     = (const float*)d_in[8];
  const float* gb     = (const float*)d_in[9];
  const float* gn_w   = (const float*)d_in[10];
  const float* ln2_w  = (const float*)d_in[11];
  const float* ln2_b  = (const float*)d_in[12];
  const float* up_w   = (const float*)d_in[13];
  const float* up_b   = (const float*)d_in[14];
  const float* dn_w   = (const float*)d_in[15];
  const float* dn_b   = (const float*)d_in[16];
  const float* post_w = (const float*)d_in[17];
  const float* post_b = (const float*)d_in[18];
  const float* W_proj = (const float*)d_in[19];
  const float* b_proj = (const float*)d_in[20];
  float* out = (float*)d_out;

  const size_t oWu   = 0;          // [2][768][256] bf16 : 1,572,864
  const size_t oWd   = 1572864;    // [2][256][384] bf16 :   786,432
  const size_t oWg2  = 2359296;    // [2][8][128][64] bf16 :  262,144
  const size_t oRgt  = 2621440;    // [2][16][64][64] bf16 :  524,288
  const size_t oWp   = 3145728;    // [96][16128] bf16 : 3,096,576
  const size_t oChunk = 6242304;
  const size_t per_seq = (size_t)3584*NS;   // 225,792 B
  int Nc = 0;
  const int cands[3] = {1024, 512, 256};
  for (int i = 0; i < 3; ++i)
    if (oChunk + (size_t)cands[i]*per_seq <= ws_size){ Nc = cands[i]; break; }
  if (Nc == 0) return;

  char* wsb = (char*)d_ws;
  u16* Wu   = (u16*)(wsb + oWu);
  u16* Wd   = (u16*)(wsb + oWd);
  u16* Wg2  = (u16*)(wsb + oWg2);
  u16* Rgt  = (u16*)(wsb + oRgt);
  u16* Wtp  = (u16*)(wsb + oWp);

  for (int blk = 0; blk < 2; ++blk){
    cvt_transpose_t<<<dim3(8, 24), 256, 0, stream>>>(
        up_w + (size_t)blk*256*768, Wu + (size_t)blk*768*256, 256, 768);
    cvt_transpose_t<<<dim3(12, 8), 256, 0, stream>>>(
        dn_w + (size_t)blk*384*256, Wd + (size_t)blk*256*384, 384, 256);
  }
  cvt_gateW2<<<16, 256, 0, stream>>>(Wg, Wg2);
  cvt_gate<<<32, 256, 0, stream>>>(Rg, Rgt);
  cvt_transpose_t<<<dim3(504, 3), 256, 0, stream>>>(W_proj, Wtp, 16128, 96);

  for (int n0 = 0; n0 < NSEQ; n0 += Nc){
    const int    nc  = (NSEQ - n0 < Nc) ? (NSEQ - n0) : Nc;
    const size_t Tc  = (size_t)nc * NS;
    char* cb = wsb + oChunk;
    u16*   h_c   = (u16*)cb;                          // Tc*512 B
    u16*   bufA  = (u16*)(cb + Tc*512);               // Tc*512 B
    u16*   bufB  = (u16*)(cb + Tc*1024);              // Tc*512 B
    u16*   gates = (u16*)(cb + Tc*1536);              // Tc*2048 B
    u16*   gp    = gates;                             // reuse (Tc*768 B)
    float* ptmp  = (float*)(cb + Tc*1536 + Tc*1024);  // overlay in gates tail
    const int t_base = n0*NS;
    const int Tci = (int)Tc;

    patch_embed_ln_v<<<Tci/4, 256, 0, stream>>>(
        x, W_emb, b_emb, ln1_w, ln1_b, h_c, bufA, t_base);

    for (int blk = 0; blk < 2; ++blk){
      if (blk == 1)
        layernorm_v<<<Tci/4, 256, 0, stream>>>(h_c, ln1_w + DDIM, ln1_b + DDIM, bufA);
      conv_silu_v<<<Tci/4, 256, 0, stream>>>(bufA, conv_w + blk*4*DDIM, conv_b + blk*DDIM, bufB);
      mfma_gate2<<<dim3(8, Tci/128), 256, 0, stream>>>(
          bufB, bufA, Wg2 + (size_t)blk*8*8192, gb + blk*4*DDIM, gates);
      slstm_scan5<<<dim3(nc/4, NHEAD), 256, 0, stream>>>(
          gates, Rgt + (size_t)blk*16*4096, bufB);
      gn_res_ln_v<<<Tci/4, 256, 0, stream>>>(
          bufB, gn_w + blk*DDIM, ln2_w + blk*DDIM, ln2_b + blk*DDIM, h_c, bufA);
      mfma_up_gelu4<<<dim3(6, Tci/128), 256, 0, stream>>>(
          bufA, Wu + (size_t)blk*768*256, up_b + blk*2*UPDIM, gp);
      mfma_gemm2<128,128,2,2,4,4,1,4><<<dim3(2, Tci/128), 256, 0, stream>>>(
          gp, UPDIM, Wd + (size_t)blk*256*384, UPDIM,
          dn_b + blk*DDIM, (void*)h_c, DDIM, 12, 0, 0);
    }

    layernorm_v<<<Tci/4, 256, 0, stream>>>(h_c, post_w, post_b, bufA);
    mfma_gemm2<64,96,2,2,2,3,2,0><<<dim3(1, nc/64, KC_PROJ), 256, 0, stream>>>(
        bufA, NS*DDIM, Wtp, NS*DDIM,
        b_proj, (void*)ptmp, PREDN, KCHUNK_PROJ/32, KCHUNK_PROJ, nc);
    proj_out<<<(nc*PREDN + 255)/256, 256, 0, stream>>>(ptmp, b_proj, out, nc, n0);
  }
}